// Round 1
// baseline (773.736 us; speedup 1.0000x reference)
//
#include <hip/hip_runtime.h>

typedef unsigned short u16;
typedef __attribute__((ext_vector_type(8))) short bf16x8;
typedef __attribute__((ext_vector_type(4))) float f32x4;

// Problem constants
// B=4, S=2048, D=1024, H=16, HD=64, M=B*S=8192
#define LD 72  // LDS leading dim (ushorts): 144B stride, 16B aligned, 2-way-conflict frag reads

__device__ __forceinline__ u16 f2b(float x) {
  union { float f; unsigned u; } c; c.f = x;
  unsigned r = (c.u + 0x7fffu + ((c.u >> 16) & 1u)) >> 16;
  return (u16)r;
}

// ---------------------------------------------------------------------------
// Transpose + fp32->bf16 convert: dst[c][r] = bf16(src[r][c]); one matrix per
// blockIdx.z (offset z*R*C in both). Grid: (R/64, C/64, nmat), 256 threads.
// ---------------------------------------------------------------------------
__global__ __launch_bounds__(256) void transpose_cvt(
    const float* __restrict__ src, u16* __restrict__ dst, int R, int C) {
  __shared__ u16 tile[64][65];
  const size_t mo = (size_t)blockIdx.z * R * C;
  const float* s = src + mo;
  u16* d = dst + mo;
  const int r0 = blockIdx.x * 64, c0 = blockIdx.y * 64;
  const int t = threadIdx.x;
#pragma unroll
  for (int rep = 0; rep < 16; ++rep) {
    int idx = rep * 256 + t;
    int i = idx >> 6, j = idx & 63;
    tile[j][i] = f2b(s[(size_t)(r0 + i) * C + c0 + j]);
  }
  __syncthreads();
#pragma unroll
  for (int rep = 0; rep < 16; ++rep) {
    int idx = rep * 256 + t;
    int jj = idx >> 6, ii = idx & 63;
    d[(size_t)(c0 + jj) * R + r0 + ii] = tile[jj][ii];
  }
}

// ---------------------------------------------------------------------------
// Pack mask int32 [B,S,S] -> bits: mp[(b*S+q)*32 + k64] bit i = mask[...k64*64+i]!=0
// ---------------------------------------------------------------------------
__global__ __launch_bounds__(256) void pack_mask(
    const int* __restrict__ m, unsigned long long* __restrict__ mp) {
  const int nw = (gridDim.x * 256) >> 6;
  const int wid = (blockIdx.x * 256 + threadIdx.x) >> 6;
  const int lane = threadIdx.x & 63;
  const int total = 4 * 2048 * 32;  // 262144
  for (int i = wid; i < total; i += nw) {
    int v = m[(size_t)i * 64 + lane];
    unsigned long long bits = __ballot(v != 0);
    if (lane == 0) mp[i] = bits;
  }
}

// ---------------------------------------------------------------------------
// Projection GEMM: out[b,h,s,e] = bf16( X[s_glob]·W[h][:,e] + bias[h,e] )
// X fp32 [8192][1024] (converted to bf16 on load), Wt bf16 [H][64][1024] (n,k),
// 64x64 tile per block, BK=64, 4 waves x (16 rows x 64 cols).
// Grid: (128, 16), 256 threads.
// ---------------------------------------------------------------------------
__global__ __launch_bounds__(256) void proj_gemm(
    const float* __restrict__ X, const u16* __restrict__ Wt,
    const float* __restrict__ bias, u16* __restrict__ outp) {
  __shared__ u16 Al[64 * LD];
  __shared__ u16 Bl[64 * LD];
  const int h = blockIdx.y;
  const int s0 = blockIdx.x * 64;
  const int t = threadIdx.x;
  const int w = t >> 6, lane = t & 63;
  const int m16 = lane & 15, q4 = lane >> 4;
  f32x4 acc[4];
#pragma unroll
  for (int g = 0; g < 4; ++g) acc[g] = (f32x4){0.f, 0.f, 0.f, 0.f};

  for (int k0 = 0; k0 < 1024; k0 += 64) {
    __syncthreads();
    // A tile: 64x64 fp32 -> bf16 LDS. 1024 float4 units, 4/thread.
#pragma unroll
    for (int rep = 0; rep < 4; ++rep) {
      int u = rep * 256 + t;
      int row = u >> 4, c4 = u & 15;
      float4 v = *(const float4*)(X + (size_t)(s0 + row) * 1024 + k0 + c4 * 4);
      u16* p = Al + row * LD + c4 * 4;
      p[0] = f2b(v.x); p[1] = f2b(v.y); p[2] = f2b(v.z); p[3] = f2b(v.w);
    }
    // B tile: 64 n-rows x 64 k: 512 16B units, 2/thread.
#pragma unroll
    for (int rep = 0; rep < 2; ++rep) {
      int u = rep * 256 + t;
      int row = u >> 3, ch = u & 7;
      *(int4*)(Bl + row * LD + ch * 8) =
          *(const int4*)(Wt + (size_t)(h * 64 + row) * 1024 + k0 + ch * 8);
    }
    __syncthreads();
#pragma unroll
    for (int ks = 0; ks < 2; ++ks) {
      bf16x8 a = *(const bf16x8*)(Al + (w * 16 + m16) * LD + ks * 32 + q4 * 8);
#pragma unroll
      for (int g = 0; g < 4; ++g) {
        bf16x8 b = *(const bf16x8*)(Bl + (g * 16 + m16) * LD + ks * 32 + q4 * 8);
        acc[g] = __builtin_amdgcn_mfma_f32_16x16x32_bf16(a, b, acc[g], 0, 0, 0);
      }
    }
  }
  const int b = s0 >> 11;
  const int sl0 = (s0 & 2047) + w * 16 + q4 * 4;
#pragma unroll
  for (int g = 0; g < 4; ++g) {
    int e = g * 16 + m16;
    float bv = bias[h * 64 + e];
#pragma unroll
    for (int r = 0; r < 4; ++r) {
      outp[(((size_t)(b * 16 + h)) * 2048 + sl0 + r) * 64 + e] = f2b(acc[g][r] + bv);
    }
  }
}

// ---------------------------------------------------------------------------
// Flash attention with mask-to-zero-before-softmax semantics.
// One block = 64 q rows of one (b,h). 4 waves x 16 rows. 64-key tiles.
// Grid: (32, 16, 4), 256 threads.
// ---------------------------------------------------------------------------
__global__ __launch_bounds__(256) void attn(
    const u16* __restrict__ qb, const u16* __restrict__ kb,
    const u16* __restrict__ vb, const unsigned long long* __restrict__ mp,
    u16* __restrict__ zb) {
  __shared__ u16 Kl[64 * LD];       // [key][hd]
  __shared__ u16 Vt[64 * LD];       // [hd][key]
  __shared__ u16 Pl[4][16 * LD];    // per-wave P [qrow16][key64]
  const int b = blockIdx.z, h = blockIdx.y, q0 = blockIdx.x * 64;
  const int t = threadIdx.x, w = t >> 6, lane = t & 63;
  const int m16 = lane & 15, q4 = lane >> 4;
  const size_t bh = (size_t)(b * 16 + h) * 2048;
  const u16* qp = qb + bh * 64;
  const u16* kp = kb + bh * 64;
  const u16* vp = vb + bh * 64;

  const int qrow = q0 + w * 16 + m16;
  bf16x8 qa[2];
  qa[0] = *(const bf16x8*)(qp + (size_t)qrow * 64 + q4 * 8);
  qa[1] = *(const bf16x8*)(qp + (size_t)qrow * 64 + 32 + q4 * 8);

  f32x4 oacc[4];
#pragma unroll
  for (int g = 0; g < 4; ++g) oacc[g] = (f32x4){0.f, 0.f, 0.f, 0.f};
  float mrow[4], lrow[4];
#pragma unroll
  for (int r = 0; r < 4; ++r) { mrow[r] = -1e30f; lrow[r] = 0.f; }

  for (int kt = 0; kt < 32; ++kt) {
    const int k0 = kt * 64;
    __syncthreads();  // prev iteration's Kl/Vt reads done
#pragma unroll
    for (int rep = 0; rep < 2; ++rep) {
      int u = rep * 256 + t;
      int row = u >> 3, ch = u & 7;
      *(int4*)(Kl + row * LD + ch * 8) =
          *(const int4*)(kp + (size_t)(k0 + row) * 64 + ch * 8);
      bf16x8 vv = *(const bf16x8*)(vp + (size_t)(k0 + row) * 64 + ch * 8);
#pragma unroll
      for (int j = 0; j < 8; ++j) Vt[(ch * 8 + j) * LD + row] = (u16)vv[j];
    }
    __syncthreads();
    // S = Q K^T  (16 q-rows x 64 keys per wave)
    f32x4 sacc[4];
#pragma unroll
    for (int g = 0; g < 4; ++g) sacc[g] = (f32x4){0.f, 0.f, 0.f, 0.f};
#pragma unroll
    for (int ks = 0; ks < 2; ++ks) {
#pragma unroll
      for (int g = 0; g < 4; ++g) {
        bf16x8 kf = *(const bf16x8*)(Kl + (g * 16 + m16) * LD + ks * 32 + q4 * 8);
        sacc[g] = __builtin_amdgcn_mfma_f32_16x16x32_bf16(qa[ks], kf, sacc[g], 0, 0, 0);
      }
    }
    // mask (score -> 0, still inside softmax) + scale
    float sv[4][4];
#pragma unroll
    for (int r = 0; r < 4; ++r) {
      unsigned long long mb =
          mp[((size_t)(b * 2048) + q0 + w * 16 + q4 * 4 + r) * 32 + kt];
#pragma unroll
      for (int g = 0; g < 4; ++g) {
        int kl = g * 16 + m16;
        sv[g][r] = ((mb >> kl) & 1ull) ? sacc[g][r] * 0.125f : 0.0f;
      }
    }
    // online softmax update; row r lives on the 16 lanes of this quad group
    float alpha[4];
#pragma unroll
    for (int r = 0; r < 4; ++r) {
      float mx = fmaxf(fmaxf(sv[0][r], sv[1][r]), fmaxf(sv[2][r], sv[3][r]));
#pragma unroll
      for (int xm = 1; xm < 16; xm <<= 1) mx = fmaxf(mx, __shfl_xor(mx, xm));
      float mn = fmaxf(mrow[r], mx);
      alpha[r] = __expf(mrow[r] - mn);
      mrow[r] = mn;
      float rs = 0.f;
#pragma unroll
      for (int g = 0; g < 4; ++g) {
        float p = __expf(sv[g][r] - mn);
        rs += p;
        Pl[w][(q4 * 4 + r) * LD + g * 16 + m16] = f2b(p);
      }
#pragma unroll
      for (int xm = 1; xm < 16; xm <<= 1) rs += __shfl_xor(rs, xm);
      lrow[r] = lrow[r] * alpha[r] + rs;
#pragma unroll
      for (int g = 0; g < 4; ++g) oacc[g][r] *= alpha[r];
    }
    __syncthreads();  // P visible (and uniform barrier across waves)
    // O += P V
#pragma unroll
    for (int ks = 0; ks < 2; ++ks) {
      bf16x8 pa = *(const bf16x8*)(Pl[w] + m16 * LD + ks * 32 + q4 * 8);
#pragma unroll
      for (int g = 0; g < 4; ++g) {
        bf16x8 vf = *(const bf16x8*)(Vt + (g * 16 + m16) * LD + ks * 32 + q4 * 8);
        oacc[g] = __builtin_amdgcn_mfma_f32_16x16x32_bf16(pa, vf, oacc[g], 0, 0, 0);
      }
    }
  }
  // epilogue: divide by softmax denom, write z[b*S+q][h*64+e]
#pragma unroll
  for (int r = 0; r < 4; ++r) {
    float inv = 1.f / lrow[r];
    size_t zr = (size_t)(b * 2048 + q0 + w * 16 + q4 * 4 + r) * 1024;
#pragma unroll
    for (int g = 0; g < 4; ++g) {
      zb[zr + h * 64 + g * 16 + m16] = f2b(oacc[g][r] * inv);
    }
  }
}

// ---------------------------------------------------------------------------
// Output GEMM: out[s][n] = Z[s]·Wo[:,n] + bo[n], fp32 out.
// Z bf16 [8192][1024], Wot bf16 [1024(n)][1024(k)]. Grid: (128,16).
// ---------------------------------------------------------------------------
__global__ __launch_bounds__(256) void out_gemm(
    const u16* __restrict__ Z, const u16* __restrict__ Wot,
    const float* __restrict__ bo, float* __restrict__ out) {
  __shared__ u16 Al[64 * LD];
  __shared__ u16 Bl[64 * LD];
  const int n0 = blockIdx.y * 64;
  const int s0 = blockIdx.x * 64;
  const int t = threadIdx.x;
  const int w = t >> 6, lane = t & 63;
  const int m16 = lane & 15, q4 = lane >> 4;
  f32x4 acc[4];
#pragma unroll
  for (int g = 0; g < 4; ++g) acc[g] = (f32x4){0.f, 0.f, 0.f, 0.f};

  for (int k0 = 0; k0 < 1024; k0 += 64) {
    __syncthreads();
#pragma unroll
    for (int rep = 0; rep < 2; ++rep) {
      int u = rep * 256 + t;
      int row = u >> 3, ch = u & 7;
      *(int4*)(Al + row * LD + ch * 8) =
          *(const int4*)(Z + (size_t)(s0 + row) * 1024 + k0 + ch * 8);
      *(int4*)(Bl + row * LD + ch * 8) =
          *(const int4*)(Wot + (size_t)(n0 + row) * 1024 + k0 + ch * 8);
    }
    __syncthreads();
#pragma unroll
    for (int ks = 0; ks < 2; ++ks) {
      bf16x8 a = *(const bf16x8*)(Al + (w * 16 + m16) * LD + ks * 32 + q4 * 8);
#pragma unroll
      for (int g = 0; g < 4; ++g) {
        bf16x8 b = *(const bf16x8*)(Bl + (g * 16 + m16) * LD + ks * 32 + q4 * 8);
        acc[g] = __builtin_amdgcn_mfma_f32_16x16x32_bf16(a, b, acc[g], 0, 0, 0);
      }
    }
  }
#pragma unroll
  for (int g = 0; g < 4; ++g) {
    int n = n0 + g * 16 + m16;
    float bv = bo[n];
#pragma unroll
    for (int r = 0; r < 4; ++r) {
      out[(size_t)(s0 + w * 16 + q4 * 4 + r) * 1024 + n] = acc[g][r] + bv;
    }
  }
}

// ---------------------------------------------------------------------------
extern "C" void kernel_launch(void* const* d_in, const int* in_sizes, int n_in,
                              void* d_out, int out_size, void* d_ws, size_t ws_size,
                              hipStream_t stream) {
  const float* x_v = (const float*)d_in[0];
  const float* x_k = (const float*)d_in[1];
  const float* x_q = (const float*)d_in[2];
  const int* mask = (const int*)d_in[3];
  const float* Wq = (const float*)d_in[4];
  const float* bq = (const float*)d_in[5];
  const float* Wk = (const float*)d_in[6];
  const float* bk = (const float*)d_in[7];
  const float* Wv = (const float*)d_in[8];
  const float* bv = (const float*)d_in[9];
  const float* Wo = (const float*)d_in[10];
  const float* bo = (const float*)d_in[11];
  float* out = (float*)d_out;

  char* ws = (char*)d_ws;
  size_t off = 0;
  auto alloc_u16 = [&](size_t n) {
    u16* p = (u16*)(ws + off);
    off += n * sizeof(u16);
    return p;
  };
  u16* wq_t = alloc_u16((size_t)16 * 64 * 1024);   // [h][e][d]
  u16* wk_t = alloc_u16((size_t)16 * 64 * 1024);
  u16* wv_t = alloc_u16((size_t)16 * 64 * 1024);
  u16* wo_t = alloc_u16((size_t)1024 * 1024);      // [n][k]
  u16* qb = alloc_u16((size_t)8192 * 1024);        // [b][h][s][e]
  u16* kb = alloc_u16((size_t)8192 * 1024);
  u16* vb = alloc_u16((size_t)8192 * 1024);
  u16* zb = alloc_u16((size_t)8192 * 1024);        // [s_glob][d]
  unsigned long long* mp = (unsigned long long*)(ws + off);
  off += (size_t)262144 * 8;

  transpose_cvt<<<dim3(16, 1, 16), 256, 0, stream>>>(Wq, wq_t, 1024, 64);
  transpose_cvt<<<dim3(16, 1, 16), 256, 0, stream>>>(Wk, wk_t, 1024, 64);
  transpose_cvt<<<dim3(16, 1, 16), 256, 0, stream>>>(Wv, wv_t, 1024, 64);
  transpose_cvt<<<dim3(16, 16, 1), 256, 0, stream>>>(Wo, wo_t, 1024, 1024);
  pack_mask<<<dim3(512), 256, 0, stream>>>(mask, mp);
  proj_gemm<<<dim3(128, 16), 256, 0, stream>>>(x_q, wq_t, bq, qb);
  proj_gemm<<<dim3(128, 16), 256, 0, stream>>>(x_k, wk_t, bk, kb);
  proj_gemm<<<dim3(128, 16), 256, 0, stream>>>(x_v, wv_t, bv, vb);
  attn<<<dim3(32, 16, 4), 256, 0, stream>>>(qb, kb, vb, mp, zb);
  out_gemm<<<dim3(128, 16), 256, 0, stream>>>(zb, wo_t, bo, out);
}

// Round 2
// 559.847 us; speedup vs baseline: 1.3820x; 1.3820x over previous
//
#include <hip/hip_runtime.h>

typedef unsigned short u16;
typedef __attribute__((ext_vector_type(8))) short bf16x8;
typedef __attribute__((ext_vector_type(4))) short bf16x4;
typedef __attribute__((ext_vector_type(4))) float f32x4;

// B=4, S=2048, D=1024, H=16, HD=64, M=B*S=8192
#define LD 72       // LDS leading dim (u16): 144B stride, 16B-aligned b128 reads
#define C_SCALE 0.18033688011112043f  // 0.125 * log2(e)

__device__ __forceinline__ u16 f2b(float x) {
  union { float f; unsigned u; } c; c.f = x;
  unsigned r = (c.u + 0x7fffu + ((c.u >> 16) & 1u)) >> 16;
  return (u16)r;
}

__device__ __forceinline__ bf16x4 pkbf4(float a, float b, float c, float d) {
  union { float f; unsigned u; } x;
  x.f = a; unsigned w0 = (x.u + 0x8000u) >> 16;
  x.f = b; unsigned w1 = (x.u + 0x8000u) & 0xffff0000u;
  x.f = c; unsigned w2 = (x.u + 0x8000u) >> 16;
  x.f = d; unsigned w3 = (x.u + 0x8000u) & 0xffff0000u;
  int2 v = { (int)(w0 | w1), (int)(w2 | w3) };
  return *(bf16x4*)&v;
}

// ---------------------------------------------------------------------------
// fp32 -> bf16 elementwise (float4 -> 4x u16), grid-stride.
// ---------------------------------------------------------------------------
__global__ __launch_bounds__(256) void cvt_bf16(
    const float4* __restrict__ src, ushort4* __restrict__ dst, int n4) {
  int stride = gridDim.x * 256;
  for (int i = blockIdx.x * 256 + threadIdx.x; i < n4; i += stride) {
    float4 v = src[i];
    ushort4 o = { f2b(v.x), f2b(v.y), f2b(v.z), f2b(v.w) };
    dst[i] = o;
  }
}

// ---------------------------------------------------------------------------
// Transpose + fp32->bf16: dst[c][r] = bf16(src[r][c]); one matrix per blockIdx.z.
// Grid: (R/64, C/64, nmat), 256 threads.
// ---------------------------------------------------------------------------
__global__ __launch_bounds__(256) void transpose_cvt(
    const float* __restrict__ src, u16* __restrict__ dst, int R, int C) {
  __shared__ u16 tile[64][65];
  const size_t mo = (size_t)blockIdx.z * R * C;
  const float* s = src + mo;
  u16* d = dst + mo;
  const int r0 = blockIdx.x * 64, c0 = blockIdx.y * 64;
  const int t = threadIdx.x;
#pragma unroll
  for (int rep = 0; rep < 16; ++rep) {
    int idx = rep * 256 + t;
    int i = idx >> 6, j = idx & 63;
    tile[j][i] = f2b(s[(size_t)(r0 + i) * C + c0 + j]);
  }
  __syncthreads();
#pragma unroll
  for (int rep = 0; rep < 16; ++rep) {
    int idx = rep * 256 + t;
    int jj = idx >> 6, ii = idx & 63;
    d[(size_t)(c0 + jj) * R + r0 + ii] = tile[jj][ii];
  }
}

// ---------------------------------------------------------------------------
// Pack mask int32 [B,S,S] -> bits: mp[(b*S+q)*32 + k64] bit i = mask!=0
// ---------------------------------------------------------------------------
__global__ __launch_bounds__(256) void pack_mask(
    const int* __restrict__ m, unsigned long long* __restrict__ mp) {
  const int nw = (gridDim.x * 256) >> 6;
  const int wid = (blockIdx.x * 256 + threadIdx.x) >> 6;
  const int lane = threadIdx.x & 63;
  const int total = 4 * 2048 * 32;  // 262144
  for (int i = wid; i < total; i += nw) {
    int v = m[(size_t)i * 64 + lane];
    unsigned long long bits = __ballot(v != 0);
    if (lane == 0) mp[i] = bits;
  }
}

// ---------------------------------------------------------------------------
// Unified GEMM: 128(s) x 64(n) tile, BK=64, 4 waves x 32 s-rows.
// A bf16 [8192][1024]; W bf16 [1024 n][1024 k] (row n = h*64+e); bias [1024].
// MODE 0: bf16 out to q/k layout [b][h][s][64]
// MODE 1: bf16 out TRANSPOSED to vt layout [b][h][e][2048]
// MODE 2: fp32 out [s][1024]
// Grid: (64, 16), 256 threads.
// ---------------------------------------------------------------------------
template <int MODE>
__global__ __launch_bounds__(256, 4) void gemm128(
    const u16* __restrict__ A, const u16* __restrict__ W,
    const float* __restrict__ bias, void* __restrict__ outp) {
  __shared__ u16 Asm[128 * LD];
  __shared__ u16 Bsm[64 * LD];
  const int s0 = blockIdx.x * 128, h = blockIdx.y;
  const int t = threadIdx.x;
  const int w = t >> 6, lane = t & 63;
  const int m16 = lane & 15, q4 = lane >> 4;
  const int ch = t & 7, r0 = t >> 3;
  f32x4 acc[2][4];
#pragma unroll
  for (int qg = 0; qg < 2; ++qg)
#pragma unroll
    for (int g = 0; g < 4; ++g) acc[qg][g] = (f32x4){0.f, 0.f, 0.f, 0.f};

  for (int k0 = 0; k0 < 1024; k0 += 64) {
    __syncthreads();
#pragma unroll
    for (int rep = 0; rep < 4; ++rep) {
      int row = r0 + rep * 32;
      *(int4*)(Asm + row * LD + ch * 8) =
          *(const int4*)(A + (size_t)(s0 + row) * 1024 + k0 + ch * 8);
    }
#pragma unroll
    for (int rep = 0; rep < 2; ++rep) {
      int row = r0 + rep * 32;
      *(int4*)(Bsm + row * LD + ch * 8) =
          *(const int4*)(W + (size_t)(h * 64 + row) * 1024 + k0 + ch * 8);
    }
    __syncthreads();
#pragma unroll
    for (int ks = 0; ks < 2; ++ks) {
      bf16x8 a0 = *(const bf16x8*)(Asm + (w * 32 + m16) * LD + ks * 32 + q4 * 8);
      bf16x8 a1 = *(const bf16x8*)(Asm + (w * 32 + 16 + m16) * LD + ks * 32 + q4 * 8);
#pragma unroll
      for (int g = 0; g < 4; ++g) {
        bf16x8 bfr = *(const bf16x8*)(Bsm + (g * 16 + m16) * LD + ks * 32 + q4 * 8);
        acc[0][g] = __builtin_amdgcn_mfma_f32_16x16x32_bf16(a0, bfr, acc[0][g], 0, 0, 0);
        acc[1][g] = __builtin_amdgcn_mfma_f32_16x16x32_bf16(a1, bfr, acc[1][g], 0, 0, 0);
      }
    }
  }

  if (MODE == 0) {
    u16* out = (u16*)outp;
#pragma unroll
    for (int qg = 0; qg < 2; ++qg)
#pragma unroll
      for (int g = 0; g < 4; ++g) {
        int e = g * 16 + m16;
        float bval = bias[h * 64 + e];
#pragma unroll
        for (int r = 0; r < 4; ++r) {
          int s = s0 + w * 32 + qg * 16 + q4 * 4 + r;
          int bi = s >> 11, sl = s & 2047;
          out[((size_t)(bi * 16 + h) * 2048 + sl) * 64 + e] = f2b(acc[qg][g][r] + bval);
        }
      }
  } else if (MODE == 2) {
    float* out = (float*)outp;
#pragma unroll
    for (int qg = 0; qg < 2; ++qg)
#pragma unroll
      for (int g = 0; g < 4; ++g) {
        int n = h * 64 + g * 16 + m16;
        float bval = bias[n];
#pragma unroll
        for (int r = 0; r < 4; ++r) {
          int s = s0 + w * 32 + qg * 16 + q4 * 4 + r;
          out[(size_t)s * 1024 + n] = acc[qg][g][r] + bval;
        }
      }
  } else {
    // MODE 1: transpose tile via LDS, write vt[b][h][e][2048] bf16
    __syncthreads();  // everyone done reading Asm
#pragma unroll
    for (int qg = 0; qg < 2; ++qg)
#pragma unroll
      for (int g = 0; g < 4; ++g) {
        int e = g * 16 + m16;
        float bval = bias[h * 64 + e];
#pragma unroll
        for (int r = 0; r < 4; ++r) {
          Asm[e * 136 + w * 32 + qg * 16 + q4 * 4 + r] = f2b(acc[qg][g][r] + bval);
        }
      }
    __syncthreads();
    u16* vt = (u16*)outp;
    const int bi = s0 >> 11, sl0 = s0 & 2047;
#pragma unroll
    for (int rep = 0; rep < 4; ++rep) {
      int unit = rep * 256 + t;
      int row = unit >> 4, c16 = unit & 15;
      *(int4*)(vt + ((size_t)(bi * 16 + h) * 64 + row) * 2048 + sl0 + c16 * 8) =
          *(const int4*)(Asm + row * 136 + c16 * 8);
    }
  }
}

// ---------------------------------------------------------------------------
// Flash attention, no-max softmax (masked scores = 0 -> p = 1 automatically).
// S^T = K·Q^T via 16x16x32 (D: row=key, col=q)  ==> registers are directly the
// A-fragment of 16x16x16 for P·V (k = quad*4 + reg). No LDS P roundtrip.
// Block: 4 waves x 32 q-rows = 128 q of one (b,h). Double-buffered K/V tiles,
// one barrier per 64-key tile. Grid: 1024 blocks (id: low 6 bits = b*16+h for
// XCD L2 locality), 256 threads.
// ---------------------------------------------------------------------------
__global__ __launch_bounds__(256, 4) void attn(
    const u16* __restrict__ qb, const u16* __restrict__ kb,
    const u16* __restrict__ vt, const unsigned long long* __restrict__ mp,
    u16* __restrict__ zb) {
  __shared__ u16 Kl[2][64 * LD];  // [key][hd]
  __shared__ u16 Vl[2][64 * LD];  // [e][key]
  const int id = blockIdx.x;
  const int qi = id >> 6;         // q-block 0..15
  const int bh = id & 63;
  const int b = bh >> 4, h = bh & 15;
  const int t = threadIdx.x, w = t >> 6, lane = t & 63;
  const int m16 = lane & 15, q4 = lane >> 4;
  const size_t bho = (size_t)bh * 2048;
  const u16* qp = qb + bho * 64;
  const u16* kp = kb + bho * 64;
  const u16* vp = vt + bho * 64;  // [e][2048]
  const int qbase = qi * 128 + w * 32;

  bf16x8 qa[2][2];
#pragma unroll
  for (int qg = 0; qg < 2; ++qg)
#pragma unroll
    for (int ks = 0; ks < 2; ++ks)
      qa[qg][ks] = *(const bf16x8*)(qp + (size_t)(qbase + qg * 16 + m16) * 64 + ks * 32 + q4 * 8);

  f32x4 oacc[2][4];
#pragma unroll
  for (int qg = 0; qg < 2; ++qg)
#pragma unroll
    for (int g = 0; g < 4; ++g) oacc[qg][g] = (f32x4){0.f, 0.f, 0.f, 0.f};
  float lsum[2] = {0.f, 0.f};

  const int ch = t & 7, rw0 = t >> 3;  // tile-load decomposition
  // prefetch tile 0
  int4 pk0 = *(const int4*)(kp + (size_t)rw0 * 64 + ch * 8);
  int4 pk1 = *(const int4*)(kp + (size_t)(rw0 + 32) * 64 + ch * 8);
  int4 pv0 = *(const int4*)(vp + (size_t)rw0 * 2048 + ch * 8);
  int4 pv1 = *(const int4*)(vp + (size_t)(rw0 + 32) * 2048 + ch * 8);
  *(int4*)(&Kl[0][rw0 * LD + ch * 8]) = pk0;
  *(int4*)(&Kl[0][(rw0 + 32) * LD + ch * 8]) = pk1;
  *(int4*)(&Vl[0][rw0 * LD + ch * 8]) = pv0;
  *(int4*)(&Vl[0][(rw0 + 32) * LD + ch * 8]) = pv1;
  __syncthreads();

  for (int kt = 0; kt < 32; ++kt) {
    const int cur = kt & 1;
    if (kt < 31) {
      const int k0n = (kt + 1) * 64;
      pk0 = *(const int4*)(kp + (size_t)(k0n + rw0) * 64 + ch * 8);
      pk1 = *(const int4*)(kp + (size_t)(k0n + rw0 + 32) * 64 + ch * 8);
      pv0 = *(const int4*)(vp + (size_t)rw0 * 2048 + k0n + ch * 8);
      pv1 = *(const int4*)(vp + (size_t)(rw0 + 32) * 2048 + k0n + ch * 8);
    }
    const unsigned long long mb0 = mp[((size_t)b * 2048 + qbase + m16) * 32 + kt];
    const unsigned long long mb1 = mp[((size_t)b * 2048 + qbase + 16 + m16) * 32 + kt];

#pragma unroll
    for (int g = 0; g < 4; ++g) {
      bf16x8 kf0 = *(const bf16x8*)(&Kl[cur][(g * 16 + m16) * LD + q4 * 8]);
      bf16x8 kf1 = *(const bf16x8*)(&Kl[cur][(g * 16 + m16) * LD + 32 + q4 * 8]);
      f32x4 s0 = (f32x4){0.f, 0.f, 0.f, 0.f};
      f32x4 s1 = (f32x4){0.f, 0.f, 0.f, 0.f};
      s0 = __builtin_amdgcn_mfma_f32_16x16x32_bf16(kf0, qa[0][0], s0, 0, 0, 0);
      s0 = __builtin_amdgcn_mfma_f32_16x16x32_bf16(kf1, qa[0][1], s0, 0, 0, 0);
      s1 = __builtin_amdgcn_mfma_f32_16x16x32_bf16(kf0, qa[1][0], s1, 0, 0, 0);
      s1 = __builtin_amdgcn_mfma_f32_16x16x32_bf16(kf1, qa[1][1], s1, 0, 0, 0);
      const unsigned nib0 = (unsigned)(mb0 >> (g * 16 + q4 * 4)) & 0xFu;
      const unsigned nib1 = (unsigned)(mb1 >> (g * 16 + q4 * 4)) & 0xFu;
      float p0[4], p1[4];
#pragma unroll
      for (int r = 0; r < 4; ++r) {
        float t0 = s0[r] * C_SCALE;
        float t1 = s1[r] * C_SCALE;
        t0 = (nib0 & (1u << r)) ? t0 : 0.f;
        t1 = (nib1 & (1u << r)) ? t1 : 0.f;
        p0[r] = __builtin_amdgcn_exp2f(t0);
        p1[r] = __builtin_amdgcn_exp2f(t1);
      }
      lsum[0] += (p0[0] + p0[1]) + (p0[2] + p0[3]);
      lsum[1] += (p1[0] + p1[1]) + (p1[2] + p1[3]);
      bf16x4 pa0 = pkbf4(p0[0], p0[1], p0[2], p0[3]);
      bf16x4 pa1 = pkbf4(p1[0], p1[1], p1[2], p1[3]);
#pragma unroll
      for (int e = 0; e < 4; ++e) {
        bf16x4 vf = *(const bf16x4*)(&Vl[cur][(e * 16 + m16) * LD + g * 16 + q4 * 4]);
        oacc[0][e] = __builtin_amdgcn_mfma_f32_16x16x16bf16_1k(pa0, vf, oacc[0][e], 0, 0, 0);
        oacc[1][e] = __builtin_amdgcn_mfma_f32_16x16x16bf16_1k(pa1, vf, oacc[1][e], 0, 0, 0);
      }
    }

    if (kt < 31) {
      const int nxt = cur ^ 1;
      *(int4*)(&Kl[nxt][rw0 * LD + ch * 8]) = pk0;
      *(int4*)(&Kl[nxt][(rw0 + 32) * LD + ch * 8]) = pk1;
      *(int4*)(&Vl[nxt][rw0 * LD + ch * 8]) = pv0;
      *(int4*)(&Vl[nxt][(rw0 + 32) * LD + ch * 8]) = pv1;
      __syncthreads();
    }
  }

  // final softmax denominators: reduce across quads (keys live on quads+regs)
#pragma unroll
  for (int qg = 0; qg < 2; ++qg) {
    float l = lsum[qg];
    l += __shfl_xor(l, 16);
    l += __shfl_xor(l, 32);
    lsum[qg] = l;
  }
  // epilogue: O[q][e] / l[q]; lane holds q = qbase + qg*16 + q4*4 + r, e = eblk*16+m16
#pragma unroll
  for (int qg = 0; qg < 2; ++qg) {
#pragma unroll
    for (int r = 0; r < 4; ++r) {
      float inv = 1.f / __shfl(lsum[qg], q4 * 4 + r);
      size_t zr = ((size_t)b * 2048 + qbase + qg * 16 + q4 * 4 + r) * 1024 + h * 64;
#pragma unroll
      for (int e = 0; e < 4; ++e) {
        zb[zr + e * 16 + m16] = f2b(oacc[qg][e][r] * inv);
      }
    }
  }
}

// ---------------------------------------------------------------------------
extern "C" void kernel_launch(void* const* d_in, const int* in_sizes, int n_in,
                              void* d_out, int out_size, void* d_ws, size_t ws_size,
                              hipStream_t stream) {
  const float* x_v = (const float*)d_in[0];
  const float* x_k = (const float*)d_in[1];
  const float* x_q = (const float*)d_in[2];
  const int* mask = (const int*)d_in[3];
  const float* Wq = (const float*)d_in[4];
  const float* bq = (const float*)d_in[5];
  const float* Wk = (const float*)d_in[6];
  const float* bk = (const float*)d_in[7];
  const float* Wv = (const float*)d_in[8];
  const float* bv = (const float*)d_in[9];
  const float* Wo = (const float*)d_in[10];
  const float* bo = (const float*)d_in[11];
  float* out = (float*)d_out;

  char* ws = (char*)d_ws;
  size_t off = 0;
  auto alloc_u16 = [&](size_t n) {
    u16* p = (u16*)(ws + off);
    off += n * sizeof(u16);
    return p;
  };
  u16* wq_t = alloc_u16((size_t)16 * 64 * 1024);  // [h][e][d] == [1024 n][1024 k]
  u16* wk_t = alloc_u16((size_t)16 * 64 * 1024);
  u16* wv_t = alloc_u16((size_t)16 * 64 * 1024);
  u16* wo_t = alloc_u16((size_t)1024 * 1024);     // [n][k]
  u16* qb = alloc_u16((size_t)8192 * 1024);       // [b][h][s][e]
  u16* kb = alloc_u16((size_t)8192 * 1024);
  u16* vtb = alloc_u16((size_t)8192 * 1024);      // [b][h][e][s]
  u16* xq16 = alloc_u16((size_t)8192 * 1024);     // also reused as zb
  u16* xk16 = alloc_u16((size_t)8192 * 1024);
  u16* xv16 = alloc_u16((size_t)8192 * 1024);
  unsigned long long* mp = (unsigned long long*)(ws + off);
  off += (size_t)262144 * 8;
  u16* zb = xq16;  // xq16 dead after q-projection; alias saves 16 MB

  transpose_cvt<<<dim3(16, 1, 16), 256, 0, stream>>>(Wq, wq_t, 1024, 64);
  transpose_cvt<<<dim3(16, 1, 16), 256, 0, stream>>>(Wk, wk_t, 1024, 64);
  transpose_cvt<<<dim3(16, 1, 16), 256, 0, stream>>>(Wv, wv_t, 1024, 64);
  transpose_cvt<<<dim3(16, 16, 1), 256, 0, stream>>>(Wo, wo_t, 1024, 1024);
  pack_mask<<<dim3(1024), 256, 0, stream>>>(mask, mp);
  const int n4 = 8192 * 1024 / 4;
  cvt_bf16<<<dim3(1024), 256, 0, stream>>>((const float4*)x_q, (ushort4*)xq16, n4);
  cvt_bf16<<<dim3(1024), 256, 0, stream>>>((const float4*)x_k, (ushort4*)xk16, n4);
  cvt_bf16<<<dim3(1024), 256, 0, stream>>>((const float4*)x_v, (ushort4*)xv16, n4);
  gemm128<0><<<dim3(64, 16), 256, 0, stream>>>(xq16, wq_t, bq, qb);
  gemm128<0><<<dim3(64, 16), 256, 0, stream>>>(xk16, wk_t, bk, kb);
  gemm128<1><<<dim3(64, 16), 256, 0, stream>>>(xv16, wv_t, bv, vtb);
  attn<<<dim3(1024), 256, 0, stream>>>(qb, kb, vtb, mp, zb);
  gemm128<2><<<dim3(64, 16), 256, 0, stream>>>(zb, wo_t, bo, out);
}

// Round 4
// 448.814 us; speedup vs baseline: 1.7240x; 1.2474x over previous
//
#include <hip/hip_runtime.h>

typedef unsigned short u16;
typedef unsigned long long u64;
typedef __attribute__((ext_vector_type(8))) short bf16x8;
typedef __attribute__((ext_vector_type(4))) float f32x4;

// B=4, S=2048, D=1024, H=16, HD=64, M=B*S=8192
#define LD 72                          // attn LDS leading dim (u16)
#define C_SCALE 0.18033688011112043f   // 0.125 * log2(e), folded into Q

__device__ __forceinline__ u16 f2b(float x) {
  union { float f; unsigned u; } c; c.f = x;
  unsigned r = (c.u + 0x7fffu + ((c.u >> 16) & 1u)) >> 16;
  return (u16)r;
}

__device__ __forceinline__ unsigned pk2(float a, float b) {
#if __has_builtin(__builtin_amdgcn_cvt_pk_bf16_f32)
  typedef __attribute__((ext_vector_type(2))) __bf16 b2;
  b2 r = __builtin_amdgcn_cvt_pk_bf16_f32(a, b);
  union { b2 v; unsigned u; } c; c.v = r;
  return c.u;
#else
  union { float f; unsigned u; } x, y;
  x.f = a; y.f = b;
  return ((x.u + 0x8000u) >> 16) | ((y.u + 0x8000u) & 0xffff0000u);
#endif
}

__device__ __forceinline__ void gll16(const u16* g, u16* l) {
  __builtin_amdgcn_global_load_lds(
      (const __attribute__((address_space(1))) void*)g,
      (__attribute__((address_space(3))) void*)l, 16, 0, 0);
}

// ---------------------------------------------------------------------------
// fp32 -> bf16 elementwise
// ---------------------------------------------------------------------------
__global__ __launch_bounds__(256) void cvt_bf16(
    const float4* __restrict__ src, ushort4* __restrict__ dst, int n4) {
  int stride = gridDim.x * 256;
  for (int i = blockIdx.x * 256 + threadIdx.x; i < n4; i += stride) {
    float4 v = src[i];
    ushort4 o = { f2b(v.x), f2b(v.y), f2b(v.z), f2b(v.w) };
    dst[i] = o;
  }
}

// ---------------------------------------------------------------------------
// Transpose + fp32->bf16: dst[c][r] = bf16(src[r][c]); one matrix per blockIdx.z
// ---------------------------------------------------------------------------
__global__ __launch_bounds__(256) void transpose_cvt(
    const float* __restrict__ src, u16* __restrict__ dst, int R, int C) {
  __shared__ u16 tile[64][65];
  const size_t mo = (size_t)blockIdx.z * R * C;
  const float* s = src + mo;
  u16* d = dst + mo;
  const int r0 = blockIdx.x * 64, c0 = blockIdx.y * 64;
  const int t = threadIdx.x;
#pragma unroll
  for (int rep = 0; rep < 16; ++rep) {
    int idx = rep * 256 + t;
    int i = idx >> 6, j = idx & 63;
    tile[j][i] = f2b(s[(size_t)(r0 + i) * C + c0 + j]);
  }
  __syncthreads();
#pragma unroll
  for (int rep = 0; rep < 16; ++rep) {
    int idx = rep * 256 + t;
    int jj = idx >> 6, ii = idx & 63;
    d[(size_t)(c0 + jj) * R + r0 + ii] = tile[jj][ii];
  }
}

// ---------------------------------------------------------------------------
// Pack mask int32 [B,S,S] -> bits
// ---------------------------------------------------------------------------
__global__ __launch_bounds__(256) void pack_mask(
    const int* __restrict__ m, u64* __restrict__ mp) {
  const int nw = (gridDim.x * 256) >> 6;
  const int wid = (blockIdx.x * 256 + threadIdx.x) >> 6;
  const int lane = threadIdx.x & 63;
  const int total = 4 * 2048 * 32;
  for (int i = wid; i < total; i += nw) {
    int v = m[(size_t)i * 64 + lane];
    u64 bits = __ballot(v != 0);
    if (lane == 0) mp[i] = bits;
  }
}

// ---------------------------------------------------------------------------
// m97-style GEMM: 128x128 tile, BK=64, global_load_lds width-16 staging.
// A bf16 [8192][1024]; W bf16 [1024 n][1024 k]; bias [1024].
// MODE 0: bf16 out [b][h][s][64], value (acc+bias)*scale
// MODE 1: bf16 out transposed -> vt [b][h][e][2048]
// MODE 2: fp32 out [s][1024]
// Grid: (64, 8), 256 threads, 2 blocks/CU.
// ---------------------------------------------------------------------------
template <int MODE>
__global__ __launch_bounds__(256, 2) void gemm_t(
    const u16* __restrict__ A, const u16* __restrict__ W,
    const float* __restrict__ bias, void* __restrict__ outp, float scale) {
  __shared__ u16 S[17408];  // Asm 8192 + Bsm 8192; MODE1 reuses as 128x136
  u16* Asm = S;
  u16* Bsm = S + 8192;
  const int s0 = blockIdx.x * 128, n0 = blockIdx.y * 128;
  const int t = threadIdx.x, wv = t >> 6, lane = t & 63;
  const int m16 = lane & 15, q4 = lane >> 4;
  const int rsub = lane >> 3, csub = lane & 7;
  const int wr = (wv & 1) * 64, wc = (wv >> 1) * 64;
  f32x4 acc[4][4];
#pragma unroll
  for (int i = 0; i < 4; ++i)
#pragma unroll
    for (int j = 0; j < 4; ++j) acc[i][j] = (f32x4){0.f, 0.f, 0.f, 0.f};

  for (int k0 = 0; k0 < 1024; k0 += 64) {
    __syncthreads();
#pragma unroll
    for (int i = 0; i < 4; ++i) {
      int chunk = wv * 4 + i;
      gll16(A + (size_t)(s0 + chunk * 8 + rsub) * 1024 + k0 + csub * 8,
            Asm + chunk * 512 + lane * 8);
      gll16(W + (size_t)(n0 + chunk * 8 + rsub) * 1024 + k0 + csub * 8,
            Bsm + chunk * 512 + lane * 8);
    }
    __syncthreads();
#pragma unroll
    for (int ks = 0; ks < 2; ++ks) {
      bf16x8 af[4], bfr[4];
#pragma unroll
      for (int i = 0; i < 4; ++i)
        af[i] = *(const bf16x8*)(Asm + (wr + i * 16 + m16) * 64 + ks * 32 + q4 * 8);
#pragma unroll
      for (int j = 0; j < 4; ++j)
        bfr[j] = *(const bf16x8*)(Bsm + (wc + j * 16 + m16) * 64 + ks * 32 + q4 * 8);
#pragma unroll
      for (int i = 0; i < 4; ++i)
#pragma unroll
        for (int j = 0; j < 4; ++j)
          acc[i][j] = __builtin_amdgcn_mfma_f32_16x16x32_bf16(af[i], bfr[j], acc[i][j], 0, 0, 0);
    }
  }

  if (MODE == 0) {
    u16* out = (u16*)outp;
#pragma unroll
    for (int j = 0; j < 4; ++j) {
      int n = n0 + wc + j * 16 + m16;
      int h = n >> 6, e = n & 63;
      float bval = bias[n];
#pragma unroll
      for (int i = 0; i < 4; ++i)
#pragma unroll
        for (int r = 0; r < 4; ++r) {
          int s = s0 + wr + i * 16 + q4 * 4 + r;
          int bi = s >> 11, sl = s & 2047;
          out[((size_t)(bi * 16 + h) * 2048 + sl) * 64 + e] =
              f2b((acc[i][j][r] + bval) * scale);
        }
    }
  } else if (MODE == 2) {
    float* out = (float*)outp;
#pragma unroll
    for (int j = 0; j < 4; ++j) {
      int n = n0 + wc + j * 16 + m16;
      float bval = bias[n];
#pragma unroll
      for (int i = 0; i < 4; ++i)
#pragma unroll
        for (int r = 0; r < 4; ++r) {
          int s = s0 + wr + i * 16 + q4 * 4 + r;
          out[(size_t)s * 1024 + n] = acc[i][j][r] + bval;
        }
    }
  } else {
    // MODE 1: transpose through LDS (stride 136), write vt[b][h][e][2048]
    __syncthreads();
#pragma unroll
    for (int j = 0; j < 4; ++j) {
      int nl = wc + j * 16 + m16;
      float bval = bias[n0 + nl];
#pragma unroll
      for (int i = 0; i < 4; ++i)
#pragma unroll
        for (int r = 0; r < 4; ++r)
          S[nl * 136 + wr + i * 16 + q4 * 4 + r] = f2b(acc[i][j][r] + bval);
    }
    __syncthreads();
    u16* vt = (u16*)outp;
    const int bi = s0 >> 11, sl0 = s0 & 2047;
    // 128 n-rows x 128 s-cols = 2048 int4 units -> 8 reps of 256 threads.
    // (round-3 bug: rep<4 left odd heads' V^T unwritten)
#pragma unroll
    for (int rep = 0; rep < 8; ++rep) {
      int u = rep * 256 + t;
      int rr = u >> 4, cc = (u & 15) * 8;
      int n = n0 + rr, h = n >> 6, e = n & 63;
      *(int4*)(vt + ((size_t)(bi * 16 + h) * 64 + e) * 2048 + sl0 + cc) =
          *(const int4*)(S + rr * 136 + cc);
    }
  }
}

// ---------------------------------------------------------------------------
// Flash attention, no-max softmax, key-permuted K staging so PV runs K=32 MFMA,
// lsum via ones-MFMA. Block: 4 waves x 32 q = 128 q of one (b,h).
// Grid: 1024 (low 6 bits = bh), 256 threads.
// ---------------------------------------------------------------------------
__global__ __launch_bounds__(256, 4) void attn(
    const u16* __restrict__ qb, const u16* __restrict__ kb,
    const u16* __restrict__ vt, const u64* __restrict__ mp,
    u16* __restrict__ zb) {
  __shared__ u16 Kl[2][64 * LD];  // permuted-key rows
  __shared__ u16 Vl[2][64 * LD];  // [e][key] natural
  const int id = blockIdx.x;
  const int qi = id >> 6;
  const int bh = id & 63;
  const int b = bh >> 4, h = bh & 15;
  const int t = threadIdx.x, w = t >> 6, lane = t & 63;
  const int m16 = lane & 15, q4 = lane >> 4;
  const size_t bho = (size_t)bh * 2048;
  const u16* qp = qb + bho * 64;
  const u16* kp = kb + bho * 64;
  const u16* vp = vt + bho * 64;  // [e][2048]
  const int qbase = qi * 128 + w * 32;

  bf16x8 qa[2][2];
#pragma unroll
  for (int qg = 0; qg < 2; ++qg)
#pragma unroll
    for (int ks = 0; ks < 2; ++ks)
      qa[qg][ks] = *(const bf16x8*)(qp + (size_t)(qbase + qg * 16 + m16) * 64 + ks * 32 + q4 * 8);

  f32x4 oacc[2][4], lacc[2];
#pragma unroll
  for (int qg = 0; qg < 2; ++qg) {
    lacc[qg] = (f32x4){0.f, 0.f, 0.f, 0.f};
#pragma unroll
    for (int g = 0; g < 4; ++g) oacc[qg][g] = (f32x4){0.f, 0.f, 0.f, 0.f};
  }
  // ones B-fragment for row-sum MFMA (bf16 1.0 = 0x3f80)
  bf16x8 ones;
#pragma unroll
  for (int j = 0; j < 8; ++j) ones[j] = (short)0x3f80;

  const u64* mpq0 = mp + ((size_t)b * 2048 + qbase + m16) * 32;
  const u64* mpq1 = mp + ((size_t)b * 2048 + qbase + 16 + m16) * 32;

  const int ch = t & 7, rw = t >> 3;  // rw in 0..31
  // permuted K slot for row rw (within 32): set=(rw>>2)&1, m=((rw>>3)&3)*4+(rw&3)
  const int sK = (((rw >> 2) & 1) * 16) + (((rw >> 3) & 3) * 4) + (rw & 3);

  // prefetch tile 0
  int4 pk0 = *(const int4*)(kp + (size_t)rw * 64 + ch * 8);
  int4 pk1 = *(const int4*)(kp + (size_t)(rw + 32) * 64 + ch * 8);
  int4 pv0 = *(const int4*)(vp + (size_t)rw * 2048 + ch * 8);
  int4 pv1 = *(const int4*)(vp + (size_t)(rw + 32) * 2048 + ch * 8);
  *(int4*)(&Kl[0][sK * LD + ch * 8]) = pk0;
  *(int4*)(&Kl[0][(sK + 32) * LD + ch * 8]) = pk1;
  *(int4*)(&Vl[0][rw * LD + ch * 8]) = pv0;
  *(int4*)(&Vl[0][(rw + 32) * LD + ch * 8]) = pv1;
  __syncthreads();

  for (int kt = 0; kt < 32; ++kt) {
    const int cur = kt & 1;
    if (kt < 31) {
      const int k0n = (kt + 1) * 64;
      pk0 = *(const int4*)(kp + (size_t)(k0n + rw) * 64 + ch * 8);
      pk1 = *(const int4*)(kp + (size_t)(k0n + rw + 32) * 64 + ch * 8);
      pv0 = *(const int4*)(vp + (size_t)rw * 2048 + k0n + ch * 8);
      pv1 = *(const int4*)(vp + (size_t)(rw + 32) * 2048 + k0n + ch * 8);
    }
    const u64 mb0 = mpq0[kt];
    const u64 mb1 = mpq1[kt];

#pragma unroll
    for (int bb = 0; bb < 2; ++bb) {
      bf16x8 kf00 = *(const bf16x8*)(&Kl[cur][(bb * 32 + m16) * LD + q4 * 8]);
      bf16x8 kf01 = *(const bf16x8*)(&Kl[cur][(bb * 32 + m16) * LD + 32 + q4 * 8]);
      bf16x8 kf10 = *(const bf16x8*)(&Kl[cur][(bb * 32 + 16 + m16) * LD + q4 * 8]);
      bf16x8 kf11 = *(const bf16x8*)(&Kl[cur][(bb * 32 + 16 + m16) * LD + 32 + q4 * 8]);
      const unsigned by0 = (unsigned)(mb0 >> (bb * 32 + q4 * 8)) & 0xFFu;
      const unsigned by1 = (unsigned)(mb1 >> (bb * 32 + q4 * 8)) & 0xFFu;
      bf16x8 pa[2];
#pragma unroll
      for (int qg = 0; qg < 2; ++qg) {
        f32x4 sa = (f32x4){0.f, 0.f, 0.f, 0.f};
        f32x4 sb = (f32x4){0.f, 0.f, 0.f, 0.f};
        sa = __builtin_amdgcn_mfma_f32_16x16x32_bf16(kf00, qa[qg][0], sa, 0, 0, 0);
        sa = __builtin_amdgcn_mfma_f32_16x16x32_bf16(kf01, qa[qg][1], sa, 0, 0, 0);
        sb = __builtin_amdgcn_mfma_f32_16x16x32_bf16(kf10, qa[qg][0], sb, 0, 0, 0);
        sb = __builtin_amdgcn_mfma_f32_16x16x32_bf16(kf11, qa[qg][1], sb, 0, 0, 0);
        const unsigned by = qg ? by1 : by0;
        float p[8];
#pragma unroll
        for (int r = 0; r < 4; ++r) {
          p[r] = __builtin_amdgcn_exp2f((by & (1u << r)) ? sa[r] : 0.f);
          p[4 + r] = __builtin_amdgcn_exp2f((by & (1u << (4 + r))) ? sb[r] : 0.f);
        }
        union { unsigned u[4]; bf16x8 v; } pu;
        pu.u[0] = pk2(p[0], p[1]);
        pu.u[1] = pk2(p[2], p[3]);
        pu.u[2] = pk2(p[4], p[5]);
        pu.u[3] = pk2(p[6], p[7]);
        pa[qg] = pu.v;
        lacc[qg] = __builtin_amdgcn_mfma_f32_16x16x32_bf16(pa[qg], ones, lacc[qg], 0, 0, 0);
      }
#pragma unroll
      for (int e = 0; e < 4; ++e) {
        bf16x8 vf = *(const bf16x8*)(&Vl[cur][(e * 16 + m16) * LD + bb * 32 + q4 * 8]);
        oacc[0][e] = __builtin_amdgcn_mfma_f32_16x16x32_bf16(pa[0], vf, oacc[0][e], 0, 0, 0);
        oacc[1][e] = __builtin_amdgcn_mfma_f32_16x16x32_bf16(pa[1], vf, oacc[1][e], 0, 0, 0);
      }
    }

    if (kt < 31) {
      const int nxt = cur ^ 1;
      *(int4*)(&Kl[nxt][sK * LD + ch * 8]) = pk0;
      *(int4*)(&Kl[nxt][(sK + 32) * LD + ch * 8]) = pk1;
      *(int4*)(&Vl[nxt][rw * LD + ch * 8]) = pv0;
      *(int4*)(&Vl[nxt][(rw + 32) * LD + ch * 8]) = pv1;
      __syncthreads();
    }
  }

  // epilogue: lane's lacc reg r IS the denom for q-row q4*4+r (cols replicated)
#pragma unroll
  for (int qg = 0; qg < 2; ++qg) {
#pragma unroll
    for (int r = 0; r < 4; ++r) {
      float inv = 1.f / lacc[qg][r];
      size_t zr = ((size_t)b * 2048 + qbase + qg * 16 + q4 * 4 + r) * 1024 + h * 64;
#pragma unroll
      for (int e = 0; e < 4; ++e) {
        zb[zr + e * 16 + m16] = f2b(oacc[qg][e][r] * inv);
      }
    }
  }
}

// ---------------------------------------------------------------------------
extern "C" void kernel_launch(void* const* d_in, const int* in_sizes, int n_in,
                              void* d_out, int out_size, void* d_ws, size_t ws_size,
                              hipStream_t stream) {
  const float* x_v = (const float*)d_in[0];
  const float* x_k = (const float*)d_in[1];
  const float* x_q = (const float*)d_in[2];
  const int* mask = (const int*)d_in[3];
  const float* Wq = (const float*)d_in[4];
  const float* bq = (const float*)d_in[5];
  const float* Wk = (const float*)d_in[6];
  const float* bk = (const float*)d_in[7];
  const float* Wv = (const float*)d_in[8];
  const float* bv = (const float*)d_in[9];
  const float* Wo = (const float*)d_in[10];
  const float* bo = (const float*)d_in[11];
  float* out = (float*)d_out;

  char* ws = (char*)d_ws;
  size_t off = 0;
  auto alloc_u16 = [&](size_t n) {
    u16* p = (u16*)(ws + off);
    off += n * sizeof(u16);
    return p;
  };
  u16* wq_t = alloc_u16((size_t)16 * 64 * 1024);  // [h][e][d] == [1024 n][1024 k]
  u16* wk_t = alloc_u16((size_t)16 * 64 * 1024);
  u16* wv_t = alloc_u16((size_t)16 * 64 * 1024);
  u16* wo_t = alloc_u16((size_t)1024 * 1024);     // [n][k]
  u16* qb = alloc_u16((size_t)8192 * 1024);       // [b][h][s][e] (pre-scaled)
  u16* kb = alloc_u16((size_t)8192 * 1024);
  u16* vtb = alloc_u16((size_t)8192 * 1024);      // [b][h][e][s]
  u16* xq16 = alloc_u16((size_t)8192 * 1024);     // reused as zb after q-proj
  u16* xk16 = alloc_u16((size_t)8192 * 1024);
  u16* xv16 = alloc_u16((size_t)8192 * 1024);
  u64* mp = (u64*)(ws + off);
  off += (size_t)262144 * 8;
  u16* zb = xq16;

  transpose_cvt<<<dim3(16, 1, 16), 256, 0, stream>>>(Wq, wq_t, 1024, 64);
  transpose_cvt<<<dim3(16, 1, 16), 256, 0, stream>>>(Wk, wk_t, 1024, 64);
  transpose_cvt<<<dim3(16, 1, 16), 256, 0, stream>>>(Wv, wv_t, 1024, 64);
  transpose_cvt<<<dim3(16, 16, 1), 256, 0, stream>>>(Wo, wo_t, 1024, 1024);
  pack_mask<<<dim3(1024), 256, 0, stream>>>(mask, mp);
  const int n4 = 8192 * 1024 / 4;
  cvt_bf16<<<dim3(1024), 256, 0, stream>>>((const float4*)x_q, (ushort4*)xq16, n4);
  cvt_bf16<<<dim3(1024), 256, 0, stream>>>((const float4*)x_k, (ushort4*)xk16, n4);
  cvt_bf16<<<dim3(1024), 256, 0, stream>>>((const float4*)x_v, (ushort4*)xv16, n4);
  gemm_t<0><<<dim3(64, 8), 256, 0, stream>>>(xq16, wq_t, bq, qb, C_SCALE);
  gemm_t<0><<<dim3(64, 8), 256, 0, stream>>>(xk16, wk_t, bk, kb, 1.0f);
  gemm_t<1><<<dim3(64, 8), 256, 0, stream>>>(xv16, wv_t, bv, vtb, 1.0f);
  attn<<<dim3(1024), 256, 0, stream>>>(qb, kb, vtb, mp, zb);
  gemm_t<2><<<dim3(64, 8), 256, 0, stream>>>(zb, wo_t, bo, out, 1.0f);
}

// Round 5
// 420.713 us; speedup vs baseline: 1.8391x; 1.0668x over previous
//
#include <hip/hip_runtime.h>

typedef unsigned short u16;
typedef unsigned long long u64;
typedef __attribute__((ext_vector_type(8))) short bf16x8;
typedef __attribute__((ext_vector_type(4))) float f32x4;

// B=4, S=2048, D=1024, H=16, HD=64, M=B*S=8192
#define LD 72                          // attn LDS leading dim (u16)
#define C_SCALE 0.18033688011112043f   // 0.125 * log2(e), folded into Q

__device__ __forceinline__ u16 f2b(float x) {
  union { float f; unsigned u; } c; c.f = x;
  unsigned r = (c.u + 0x7fffu + ((c.u >> 16) & 1u)) >> 16;
  return (u16)r;
}

__device__ __forceinline__ unsigned pk2(float a, float b) {
#if __has_builtin(__builtin_amdgcn_cvt_pk_bf16_f32)
  typedef __attribute__((ext_vector_type(2))) __bf16 b2;
  b2 r = __builtin_amdgcn_cvt_pk_bf16_f32(a, b);
  union { b2 v; unsigned u; } c; c.v = r;
  return c.u;
#else
  union { float f; unsigned u; } x, y;
  x.f = a; y.f = b;
  return ((x.u + 0x8000u) >> 16) | ((y.u + 0x8000u) & 0xffff0000u);
#endif
}

__device__ __forceinline__ void gll16(const u16* g, u16* l) {
  __builtin_amdgcn_global_load_lds(
      (const __attribute__((address_space(1))) void*)g,
      (__attribute__((address_space(3))) void*)l, 16, 0, 0);
}

// ---------------------------------------------------------------------------
// fp32 -> bf16 for all three inputs in one dispatch. Grid (512, 3).
// ---------------------------------------------------------------------------
__global__ __launch_bounds__(256) void cvt_bf16_3(
    const float4* __restrict__ s0, const float4* __restrict__ s1,
    const float4* __restrict__ s2, ushort4* __restrict__ d0,
    ushort4* __restrict__ d1, ushort4* __restrict__ d2, int n4) {
  const int z = blockIdx.y;
  const float4* src = z == 0 ? s0 : z == 1 ? s1 : s2;
  ushort4* dst = z == 0 ? d0 : z == 1 ? d1 : d2;
  int stride = gridDim.x * 256;
  for (int i = blockIdx.x * 256 + threadIdx.x; i < n4; i += stride) {
    float4 v = src[i];
    ushort4 o = { f2b(v.x), f2b(v.y), f2b(v.z), f2b(v.w) };
    dst[i] = o;
  }
}

// ---------------------------------------------------------------------------
// All four weight transposes in one dispatch. Flat grid 1024 blocks:
//  id>>8 == 0/1/2: Wq/Wk/Wv  — 16 head-matrices of [1024][64] each
//  id>>8 == 3:     Wo [1024][1024]
// dst[c][r] = bf16(src[r][c]) per matrix.
// ---------------------------------------------------------------------------
__global__ __launch_bounds__(256) void transpose_cvt_all(
    const float* __restrict__ Wq, const float* __restrict__ Wk,
    const float* __restrict__ Wv, const float* __restrict__ Wo,
    u16* __restrict__ wq_t, u16* __restrict__ wk_t,
    u16* __restrict__ wv_t, u16* __restrict__ wo_t) {
  __shared__ u16 tile[64][65];
  const int id = blockIdx.x;
  const int which = id >> 8, sub = id & 255;
  const float* s;
  u16* d;
  int R, C, r0, c0;
  if (which < 3) {
    const float* W = which == 0 ? Wq : which == 1 ? Wk : Wv;
    u16* D = which == 0 ? wq_t : which == 1 ? wk_t : wv_t;
    int h = sub >> 4, rt = sub & 15;
    s = W + (size_t)h * 1024 * 64;
    d = D + (size_t)h * 64 * 1024;
    R = 1024; C = 64; r0 = rt * 64; c0 = 0;
  } else {
    s = Wo; d = wo_t;
    R = 1024; C = 1024; r0 = ((sub >> 4) & 15) * 64; c0 = (sub & 15) * 64;
  }
  const int t = threadIdx.x;
#pragma unroll
  for (int rep = 0; rep < 16; ++rep) {
    int idx = rep * 256 + t;
    int i = idx >> 6, j = idx & 63;
    tile[j][i] = f2b(s[(size_t)(r0 + i) * C + c0 + j]);
  }
  __syncthreads();
#pragma unroll
  for (int rep = 0; rep < 16; ++rep) {
    int idx = rep * 256 + t;
    int jj = idx >> 6, ii = idx & 63;
    d[(size_t)(c0 + jj) * R + r0 + ii] = tile[jj][ii];
  }
}

// ---------------------------------------------------------------------------
// Pack mask int32 [B,S,S] -> bits
// ---------------------------------------------------------------------------
__global__ __launch_bounds__(256) void pack_mask(
    const int* __restrict__ m, u64* __restrict__ mp) {
  const int nw = (gridDim.x * 256) >> 6;
  const int wid = (blockIdx.x * 256 + threadIdx.x) >> 6;
  const int lane = threadIdx.x & 63;
  const int total = 4 * 2048 * 32;
  for (int i = wid; i < total; i += nw) {
    int v = m[(size_t)i * 64 + lane];
    u64 bits = __ballot(v != 0);
    if (lane == 0) mp[i] = bits;
  }
}

// ---------------------------------------------------------------------------
// GEMM core: 128x128 tile, BK=64, global_load_lds width-16 staging.
// Shared by the merged QKV kernel and the output GEMM.
// ---------------------------------------------------------------------------
__device__ __forceinline__ void gemm_core(
    const u16* __restrict__ A, const u16* __restrict__ W,
    u16* Asm, u16* Bsm, int s0, int n0, int wv, int lane,
    int m16, int q4, f32x4 acc[4][4]) {
  const int rsub = lane >> 3, csub = lane & 7;
  const int wr = (wv & 1) * 64, wc = (wv >> 1) * 64;
  for (int k0 = 0; k0 < 1024; k0 += 64) {
    __syncthreads();
#pragma unroll
    for (int i = 0; i < 4; ++i) {
      int chunk = wv * 4 + i;
      gll16(A + (size_t)(s0 + chunk * 8 + rsub) * 1024 + k0 + csub * 8,
            Asm + chunk * 512 + lane * 8);
      gll16(W + (size_t)(n0 + chunk * 8 + rsub) * 1024 + k0 + csub * 8,
            Bsm + chunk * 512 + lane * 8);
    }
    __syncthreads();
#pragma unroll
    for (int ks = 0; ks < 2; ++ks) {
      bf16x8 af[4], bfr[4];
#pragma unroll
      for (int i = 0; i < 4; ++i)
        af[i] = *(const bf16x8*)(Asm + (wr + i * 16 + m16) * 64 + ks * 32 + q4 * 8);
#pragma unroll
      for (int j = 0; j < 4; ++j)
        bfr[j] = *(const bf16x8*)(Bsm + (wc + j * 16 + m16) * 64 + ks * 32 + q4 * 8);
#pragma unroll
      for (int i = 0; i < 4; ++i)
#pragma unroll
        for (int j = 0; j < 4; ++j)
          acc[i][j] = __builtin_amdgcn_mfma_f32_16x16x32_bf16(af[i], bfr[j], acc[i][j], 0, 0, 0);
    }
  }
}

// ---------------------------------------------------------------------------
// Merged QKV projection: grid (64, 8, 3) = 1536 blocks (vs 3x512 -> better
// CU residency, LDS caps at 4 blocks/CU). z=0: Q (scaled), z=1: K, z=2: V
// (transposed epilogue -> vt[b][h][e][2048]).
// ---------------------------------------------------------------------------
__global__ __launch_bounds__(256, 2) void qkv_gemm(
    const u16* __restrict__ xq, const u16* __restrict__ xk,
    const u16* __restrict__ xv, const u16* __restrict__ wq,
    const u16* __restrict__ wk, const u16* __restrict__ wv_,
    const float* __restrict__ bq, const float* __restrict__ bk,
    const float* __restrict__ bv, u16* __restrict__ qb,
    u16* __restrict__ kb, u16* __restrict__ vtb) {
  __shared__ u16 S[17408];
  u16* Asm = S;
  u16* Bsm = S + 8192;
  const int z = blockIdx.z;
  const u16* A = z == 0 ? xq : z == 1 ? xk : xv;
  const u16* W = z == 0 ? wq : z == 1 ? wk : wv_;
  const float* bias = z == 0 ? bq : z == 1 ? bk : bv;
  const int s0 = blockIdx.x * 128, n0 = blockIdx.y * 128;
  const int t = threadIdx.x, wvi = t >> 6, lane = t & 63;
  const int m16 = lane & 15, q4 = lane >> 4;
  const int wr = (wvi & 1) * 64, wc = (wvi >> 1) * 64;
  f32x4 acc[4][4];
#pragma unroll
  for (int i = 0; i < 4; ++i)
#pragma unroll
    for (int j = 0; j < 4; ++j) acc[i][j] = (f32x4){0.f, 0.f, 0.f, 0.f};

  gemm_core(A, W, Asm, Bsm, s0, n0, wvi, lane, m16, q4, acc);

  if (z < 2) {
    u16* out = z == 0 ? qb : kb;
    const float scale = z == 0 ? C_SCALE : 1.0f;
#pragma unroll
    for (int j = 0; j < 4; ++j) {
      int n = n0 + wc + j * 16 + m16;
      int h = n >> 6, e = n & 63;
      float bval = bias[n];
#pragma unroll
      for (int i = 0; i < 4; ++i)
#pragma unroll
        for (int r = 0; r < 4; ++r) {
          int s = s0 + wr + i * 16 + q4 * 4 + r;
          int bi = s >> 11, sl = s & 2047;
          out[((size_t)(bi * 16 + h) * 2048 + sl) * 64 + e] =
              f2b((acc[i][j][r] + bval) * scale);
        }
    }
  } else {
    // V: transpose through LDS (stride 136), write vt[b][h][e][2048]
    __syncthreads();
#pragma unroll
    for (int j = 0; j < 4; ++j) {
      int nl = wc + j * 16 + m16;
      float bval = bias[n0 + nl];
#pragma unroll
      for (int i = 0; i < 4; ++i)
#pragma unroll
        for (int r = 0; r < 4; ++r)
          S[nl * 136 + wr + i * 16 + q4 * 4 + r] = f2b(acc[i][j][r] + bval);
    }
    __syncthreads();
    const int bi = s0 >> 11, sl0 = s0 & 2047;
#pragma unroll
    for (int rep = 0; rep < 8; ++rep) {  // 128 x 128 tile = 2048 int4 units
      int u = rep * 256 + t;
      int rr = u >> 4, cc = (u & 15) * 8;
      int n = n0 + rr, h = n >> 6, e = n & 63;
      *(int4*)(vtb + ((size_t)(bi * 16 + h) * 64 + e) * 2048 + sl0 + cc) =
          *(const int4*)(S + rr * 136 + cc);
    }
  }
}

// ---------------------------------------------------------------------------
// Output GEMM: fp32 out [s][1024]. Grid (64, 8).
// ---------------------------------------------------------------------------
__global__ __launch_bounds__(256, 2) void out_gemm(
    const u16* __restrict__ Z, const u16* __restrict__ Wot,
    const float* __restrict__ bo, float* __restrict__ out) {
  __shared__ u16 S[17408];
  u16* Asm = S;
  u16* Bsm = S + 8192;
  const int s0 = blockIdx.x * 128, n0 = blockIdx.y * 128;
  const int t = threadIdx.x, wvi = t >> 6, lane = t & 63;
  const int m16 = lane & 15, q4 = lane >> 4;
  const int wr = (wvi & 1) * 64, wc = (wvi >> 1) * 64;
  f32x4 acc[4][4];
#pragma unroll
  for (int i = 0; i < 4; ++i)
#pragma unroll
    for (int j = 0; j < 4; ++j) acc[i][j] = (f32x4){0.f, 0.f, 0.f, 0.f};

  gemm_core(Z, Wot, Asm, Bsm, s0, n0, wvi, lane, m16, q4, acc);

#pragma unroll
  for (int j = 0; j < 4; ++j) {
    int n = n0 + wc + j * 16 + m16;
    float bval = bo[n];
#pragma unroll
    for (int i = 0; i < 4; ++i)
#pragma unroll
      for (int r = 0; r < 4; ++r) {
        int s = s0 + wr + i * 16 + q4 * 4 + r;
        out[(size_t)s * 1024 + n] = acc[i][j][r] + bval;
      }
  }
}

// ---------------------------------------------------------------------------
// Flash attention, no-max softmax, key-permuted K staging so PV runs K=32 MFMA,
// lsum via ones-MFMA, mask u64s prefetched one tile ahead.
// Block: 4 waves x 32 q = 128 q of one (b,h). Grid: 1024, 256 threads.
// ---------------------------------------------------------------------------
__global__ __launch_bounds__(256, 4) void attn(
    const u16* __restrict__ qb, const u16* __restrict__ kb,
    const u16* __restrict__ vt, const u64* __restrict__ mp,
    u16* __restrict__ zb) {
  __shared__ u16 Kl[2][64 * LD];  // permuted-key rows
  __shared__ u16 Vl[2][64 * LD];  // [e][key] natural
  const int id = blockIdx.x;
  const int qi = id >> 6;
  const int bh = id & 63;
  const int b = bh >> 4, h = bh & 15;
  const int t = threadIdx.x, w = t >> 6, lane = t & 63;
  const int m16 = lane & 15, q4 = lane >> 4;
  const size_t bho = (size_t)bh * 2048;
  const u16* qp = qb + bho * 64;
  const u16* kp = kb + bho * 64;
  const u16* vp = vt + bho * 64;  // [e][2048]
  const int qbase = qi * 128 + w * 32;

  bf16x8 qa[2][2];
#pragma unroll
  for (int qg = 0; qg < 2; ++qg)
#pragma unroll
    for (int ks = 0; ks < 2; ++ks)
      qa[qg][ks] = *(const bf16x8*)(qp + (size_t)(qbase + qg * 16 + m16) * 64 + ks * 32 + q4 * 8);

  f32x4 oacc[2][4], lacc[2];
#pragma unroll
  for (int qg = 0; qg < 2; ++qg) {
    lacc[qg] = (f32x4){0.f, 0.f, 0.f, 0.f};
#pragma unroll
    for (int g = 0; g < 4; ++g) oacc[qg][g] = (f32x4){0.f, 0.f, 0.f, 0.f};
  }
  bf16x8 ones;
#pragma unroll
  for (int j = 0; j < 8; ++j) ones[j] = (short)0x3f80;

  const u64* mpq0 = mp + ((size_t)b * 2048 + qbase + m16) * 32;
  const u64* mpq1 = mp + ((size_t)b * 2048 + qbase + 16 + m16) * 32;

  const int ch = t & 7, rw = t >> 3;  // rw in 0..31
  const int sK = (((rw >> 2) & 1) * 16) + (((rw >> 3) & 3) * 4) + (rw & 3);

  // prefetch tile 0 + mask 0
  int4 pk0 = *(const int4*)(kp + (size_t)rw * 64 + ch * 8);
  int4 pk1 = *(const int4*)(kp + (size_t)(rw + 32) * 64 + ch * 8);
  int4 pv0 = *(const int4*)(vp + (size_t)rw * 2048 + ch * 8);
  int4 pv1 = *(const int4*)(vp + (size_t)(rw + 32) * 2048 + ch * 8);
  u64 mb0 = mpq0[0], mb1 = mpq1[0];
  *(int4*)(&Kl[0][sK * LD + ch * 8]) = pk0;
  *(int4*)(&Kl[0][(sK + 32) * LD + ch * 8]) = pk1;
  *(int4*)(&Vl[0][rw * LD + ch * 8]) = pv0;
  *(int4*)(&Vl[0][(rw + 32) * LD + ch * 8]) = pv1;
  __syncthreads();

  for (int kt = 0; kt < 32; ++kt) {
    const int cur = kt & 1;
    u64 nmb0, nmb1;
    if (kt < 31) {
      const int k0n = (kt + 1) * 64;
      pk0 = *(const int4*)(kp + (size_t)(k0n + rw) * 64 + ch * 8);
      pk1 = *(const int4*)(kp + (size_t)(k0n + rw + 32) * 64 + ch * 8);
      pv0 = *(const int4*)(vp + (size_t)rw * 2048 + k0n + ch * 8);
      pv1 = *(const int4*)(vp + (size_t)(rw + 32) * 2048 + k0n + ch * 8);
      nmb0 = mpq0[kt + 1];
      nmb1 = mpq1[kt + 1];
    }

#pragma unroll
    for (int bb = 0; bb < 2; ++bb) {
      bf16x8 kf00 = *(const bf16x8*)(&Kl[cur][(bb * 32 + m16) * LD + q4 * 8]);
      bf16x8 kf01 = *(const bf16x8*)(&Kl[cur][(bb * 32 + m16) * LD + 32 + q4 * 8]);
      bf16x8 kf10 = *(const bf16x8*)(&Kl[cur][(bb * 32 + 16 + m16) * LD + q4 * 8]);
      bf16x8 kf11 = *(const bf16x8*)(&Kl[cur][(bb * 32 + 16 + m16) * LD + 32 + q4 * 8]);
      const unsigned by0 = (unsigned)(mb0 >> (bb * 32 + q4 * 8)) & 0xFFu;
      const unsigned by1 = (unsigned)(mb1 >> (bb * 32 + q4 * 8)) & 0xFFu;
      bf16x8 pa[2];
#pragma unroll
      for (int qg = 0; qg < 2; ++qg) {
        f32x4 sa = (f32x4){0.f, 0.f, 0.f, 0.f};
        f32x4 sb = (f32x4){0.f, 0.f, 0.f, 0.f};
        sa = __builtin_amdgcn_mfma_f32_16x16x32_bf16(kf00, qa[qg][0], sa, 0, 0, 0);
        sa = __builtin_amdgcn_mfma_f32_16x16x32_bf16(kf01, qa[qg][1], sa, 0, 0, 0);
        sb = __builtin_amdgcn_mfma_f32_16x16x32_bf16(kf10, qa[qg][0], sb, 0, 0, 0);
        sb = __builtin_amdgcn_mfma_f32_16x16x32_bf16(kf11, qa[qg][1], sb, 0, 0, 0);
        const unsigned by = qg ? by1 : by0;
        float p[8];
#pragma unroll
        for (int r = 0; r < 4; ++r) {
          p[r] = __builtin_amdgcn_exp2f((by & (1u << r)) ? sa[r] : 0.f);
          p[4 + r] = __builtin_amdgcn_exp2f((by & (1u << (4 + r))) ? sb[r] : 0.f);
        }
        union { unsigned u[4]; bf16x8 v; } pu;
        pu.u[0] = pk2(p[0], p[1]);
        pu.u[1] = pk2(p[2], p[3]);
        pu.u[2] = pk2(p[4], p[5]);
        pu.u[3] = pk2(p[6], p[7]);
        pa[qg] = pu.v;
        lacc[qg] = __builtin_amdgcn_mfma_f32_16x16x32_bf16(pa[qg], ones, lacc[qg], 0, 0, 0);
      }
#pragma unroll
      for (int e = 0; e < 4; ++e) {
        bf16x8 vf = *(const bf16x8*)(&Vl[cur][(e * 16 + m16) * LD + bb * 32 + q4 * 8]);
        oacc[0][e] = __builtin_amdgcn_mfma_f32_16x16x32_bf16(pa[0], vf, oacc[0][e], 0, 0, 0);
        oacc[1][e] = __builtin_amdgcn_mfma_f32_16x16x32_bf16(pa[1], vf, oacc[1][e], 0, 0, 0);
      }
    }

    if (kt < 31) {
      const int nxt = cur ^ 1;
      *(int4*)(&Kl[nxt][sK * LD + ch * 8]) = pk0;
      *(int4*)(&Kl[nxt][(sK + 32) * LD + ch * 8]) = pk1;
      *(int4*)(&Vl[nxt][rw * LD + ch * 8]) = pv0;
      *(int4*)(&Vl[nxt][(rw + 32) * LD + ch * 8]) = pv1;
      mb0 = nmb0;
      mb1 = nmb1;
      __syncthreads();
    }
  }

  // epilogue: lane's lacc reg r IS the denom for q-row q4*4+r (cols replicated)
#pragma unroll
  for (int qg = 0; qg < 2; ++qg) {
#pragma unroll
    for (int r = 0; r < 4; ++r) {
      float inv = 1.f / lacc[qg][r];
      size_t zr = ((size_t)b * 2048 + qbase + qg * 16 + q4 * 4 + r) * 1024 + h * 64;
#pragma unroll
      for (int e = 0; e < 4; ++e) {
        zb[zr + e * 16 + m16] = f2b(oacc[qg][e][r] * inv);
      }
    }
  }
}

// ---------------------------------------------------------------------------
extern "C" void kernel_launch(void* const* d_in, const int* in_sizes, int n_in,
                              void* d_out, int out_size, void* d_ws, size_t ws_size,
                              hipStream_t stream) {
  const float* x_v = (const float*)d_in[0];
  const float* x_k = (const float*)d_in[1];
  const float* x_q = (const float*)d_in[2];
  const int* mask = (const int*)d_in[3];
  const float* Wq = (const float*)d_in[4];
  const float* bq = (const float*)d_in[5];
  const float* Wk = (const float*)d_in[6];
  const float* bk = (const float*)d_in[7];
  const float* Wv = (const float*)d_in[8];
  const float* bv = (const float*)d_in[9];
  const float* Wo = (const float*)d_in[10];
  const float* bo = (const float*)d_in[11];
  float* out = (float*)d_out;

  char* ws = (char*)d_ws;
  size_t off = 0;
  auto alloc_u16 = [&](size_t n) {
    u16* p = (u16*)(ws + off);
    off += n * sizeof(u16);
    return p;
  };
  u16* wq_t = alloc_u16((size_t)16 * 64 * 1024);  // [h][e][d]
  u16* wk_t = alloc_u16((size_t)16 * 64 * 1024);
  u16* wv_t = alloc_u16((size_t)16 * 64 * 1024);
  u16* wo_t = alloc_u16((size_t)1024 * 1024);     // [n][k]
  u16* qb = alloc_u16((size_t)8192 * 1024);       // [b][h][s][e] (pre-scaled)
  u16* kb = alloc_u16((size_t)8192 * 1024);
  u16* vtb = alloc_u16((size_t)8192 * 1024);      // [b][h][e][s]
  u16* xq16 = alloc_u16((size_t)8192 * 1024);     // reused as zb after q-proj
  u16* xk16 = alloc_u16((size_t)8192 * 1024);
  u16* xv16 = alloc_u16((size_t)8192 * 1024);
  u64* mp = (u64*)(ws + off);
  off += (size_t)262144 * 8;
  u16* zb = xq16;

  transpose_cvt_all<<<dim3(1024), 256, 0, stream>>>(
      Wq, Wk, Wv, Wo, wq_t, wk_t, wv_t, wo_t);
  pack_mask<<<dim3(1024), 256, 0, stream>>>(mask, mp);
  const int n4 = 8192 * 1024 / 4;
  cvt_bf16_3<<<dim3(512, 3), 256, 0, stream>>>(
      (const float4*)x_q, (const float4*)x_k, (const float4*)x_v,
      (ushort4*)xq16, (ushort4*)xk16, (ushort4*)xv16, n4);
  qkv_gemm<<<dim3(64, 8, 3), 256, 0, stream>>>(
      xq16, xk16, xv16, wq_t, wk_t, wv_t, bq, bk, bv, qb, kb, vtb);
  attn<<<dim3(1024), 256, 0, stream>>>(qb, kb, vtb, mp, zb);
  out_gemm<<<dim3(64, 8), 256, 0, stream>>>(zb, wo_t, bo, out);
}

// Round 6
// 402.420 us; speedup vs baseline: 1.9227x; 1.0455x over previous
//
#include <hip/hip_runtime.h>

typedef unsigned short u16;
typedef unsigned long long u64;
typedef __attribute__((ext_vector_type(8))) short bf16x8;
typedef __attribute__((ext_vector_type(4))) float f32x4;

// B=4, S=2048, D=1024, H=16, HD=64, M=B*S=8192
#define LD 72                          // attn LDS leading dim (u16)
#define C_SCALE 0.18033688011112043f   // 0.125 * log2(e), folded into Q

__device__ __forceinline__ u16 f2b(float x) {
  union { float f; unsigned u; } c; c.f = x;
  unsigned r = (c.u + 0x7fffu + ((c.u >> 16) & 1u)) >> 16;
  return (u16)r;
}

__device__ __forceinline__ unsigned pk2(float a, float b) {
#if __has_builtin(__builtin_amdgcn_cvt_pk_bf16_f32)
  typedef __attribute__((ext_vector_type(2))) __bf16 b2;
  b2 r = __builtin_amdgcn_cvt_pk_bf16_f32(a, b);
  union { b2 v; unsigned u; } c; c.v = r;
  return c.u;
#else
  union { float f; unsigned u; } x, y;
  x.f = a; y.f = b;
  return ((x.u + 0x8000u) >> 16) | ((y.u + 0x8000u) & 0xffff0000u);
#endif
}

// bf16 (lo/hi half of u32) -> f32 multiplier; exact for 0.0/1.0
__device__ __forceinline__ float blo(int w) {
  union { int i; float f; } c; c.i = w << 16; return c.f;
}
__device__ __forceinline__ float bhi(int w) {
  union { int i; float f; } c; c.i = w & 0xffff0000; return c.f;
}

__device__ __forceinline__ void gll16(const u16* g, u16* l) {
  __builtin_amdgcn_global_load_lds(
      (const __attribute__((address_space(1))) void*)g,
      (__attribute__((address_space(3))) void*)l, 16, 0, 0);
}

// ---------------------------------------------------------------------------
// fp32 -> bf16 for all three inputs in one dispatch. Grid (512, 3).
// ---------------------------------------------------------------------------
__global__ __launch_bounds__(256) void cvt_bf16_3(
    const float4* __restrict__ s0, const float4* __restrict__ s1,
    const float4* __restrict__ s2, ushort4* __restrict__ d0,
    ushort4* __restrict__ d1, ushort4* __restrict__ d2, int n4) {
  const int z = blockIdx.y;
  const float4* src = z == 0 ? s0 : z == 1 ? s1 : s2;
  ushort4* dst = z == 0 ? d0 : z == 1 ? d1 : d2;
  int stride = gridDim.x * 256;
  for (int i = blockIdx.x * 256 + threadIdx.x; i < n4; i += stride) {
    float4 v = src[i];
    ushort4 o = { f2b(v.x), f2b(v.y), f2b(v.z), f2b(v.w) };
    dst[i] = o;
  }
}

// ---------------------------------------------------------------------------
// All four weight transposes in one dispatch. Flat grid 1024 blocks.
// ---------------------------------------------------------------------------
__global__ __launch_bounds__(256) void transpose_cvt_all(
    const float* __restrict__ Wq, const float* __restrict__ Wk,
    const float* __restrict__ Wv, const float* __restrict__ Wo,
    u16* __restrict__ wq_t, u16* __restrict__ wk_t,
    u16* __restrict__ wv_t, u16* __restrict__ wo_t) {
  __shared__ u16 tile[64][65];
  const int id = blockIdx.x;
  const int which = id >> 8, sub = id & 255;
  const float* s;
  u16* d;
  int R, C, r0, c0;
  if (which < 3) {
    const float* W = which == 0 ? Wq : which == 1 ? Wk : Wv;
    u16* D = which == 0 ? wq_t : which == 1 ? wk_t : wv_t;
    int h = sub >> 4, rt = sub & 15;
    s = W + (size_t)h * 1024 * 64;
    d = D + (size_t)h * 64 * 1024;
    R = 1024; C = 64; r0 = rt * 64; c0 = 0;
  } else {
    s = Wo; d = wo_t;
    R = 1024; C = 1024; r0 = ((sub >> 4) & 15) * 64; c0 = (sub & 15) * 64;
  }
  const int t = threadIdx.x;
#pragma unroll
  for (int rep = 0; rep < 16; ++rep) {
    int idx = rep * 256 + t;
    int i = idx >> 6, j = idx & 63;
    tile[j][i] = f2b(s[(size_t)(r0 + i) * C + c0 + j]);
  }
  __syncthreads();
#pragma unroll
  for (int rep = 0; rep < 16; ++rep) {
    int idx = rep * 256 + t;
    int jj = idx >> 6, ii = idx & 63;
    d[(size_t)(c0 + jj) * R + r0 + ii] = tile[jj][ii];
  }
}

// ---------------------------------------------------------------------------
// Expand mask int32 [B,S,S] -> bf16 {1.0, 0.0} [B,S,S] (elementwise).
// ---------------------------------------------------------------------------
__global__ __launch_bounds__(256) void expand_mask(
    const int4* __restrict__ m, ushort4* __restrict__ mb, int n4) {
  int stride = gridDim.x * 256;
  for (int i = blockIdx.x * 256 + threadIdx.x; i < n4; i += stride) {
    int4 v = m[i];
    ushort4 o = { (u16)(v.x ? 0x3f80 : 0), (u16)(v.y ? 0x3f80 : 0),
                  (u16)(v.z ? 0x3f80 : 0), (u16)(v.w ? 0x3f80 : 0) };
    mb[i] = o;
  }
}

// ---------------------------------------------------------------------------
// GEMM core: 128x128 tile, BK=64, global_load_lds width-16 staging.
// ---------------------------------------------------------------------------
__device__ __forceinline__ void gemm_core(
    const u16* __restrict__ A, const u16* __restrict__ W,
    u16* Asm, u16* Bsm, int s0, int n0, int wv, int lane,
    int m16, int q4, f32x4 acc[4][4]) {
  const int rsub = lane >> 3, csub = lane & 7;
  const int wr = (wv & 1) * 64, wc = (wv >> 1) * 64;
  for (int k0 = 0; k0 < 1024; k0 += 64) {
    __syncthreads();
#pragma unroll
    for (int i = 0; i < 4; ++i) {
      int chunk = wv * 4 + i;
      gll16(A + (size_t)(s0 + chunk * 8 + rsub) * 1024 + k0 + csub * 8,
            Asm + chunk * 512 + lane * 8);
      gll16(W + (size_t)(n0 + chunk * 8 + rsub) * 1024 + k0 + csub * 8,
            Bsm + chunk * 512 + lane * 8);
    }
    __syncthreads();
#pragma unroll
    for (int ks = 0; ks < 2; ++ks) {
      bf16x8 af[4], bfr[4];
#pragma unroll
      for (int i = 0; i < 4; ++i)
        af[i] = *(const bf16x8*)(Asm + (wr + i * 16 + m16) * 64 + ks * 32 + q4 * 8);
#pragma unroll
      for (int j = 0; j < 4; ++j)
        bfr[j] = *(const bf16x8*)(Bsm + (wc + j * 16 + m16) * 64 + ks * 32 + q4 * 8);
#pragma unroll
      for (int i = 0; i < 4; ++i)
#pragma unroll
        for (int j = 0; j < 4; ++j)
          acc[i][j] = __builtin_amdgcn_mfma_f32_16x16x32_bf16(af[i], bfr[j], acc[i][j], 0, 0, 0);
    }
  }
}

// ---------------------------------------------------------------------------
// Merged QKV projection: grid (64, 8, 3). z=0: Q (scaled), z=1: K, z=2: V
// (transposed epilogue -> vt[b][h][e][2048]). (256,3): 3 blocks/CU.
// ---------------------------------------------------------------------------
__global__ __launch_bounds__(256, 3) void qkv_gemm(
    const u16* __restrict__ xq, const u16* __restrict__ xk,
    const u16* __restrict__ xv, const u16* __restrict__ wq,
    const u16* __restrict__ wk, const u16* __restrict__ wv_,
    const float* __restrict__ bq, const float* __restrict__ bk,
    const float* __restrict__ bv, u16* __restrict__ qb,
    u16* __restrict__ kb, u16* __restrict__ vtb) {
  __shared__ u16 S[17408];
  u16* Asm = S;
  u16* Bsm = S + 8192;
  const int z = blockIdx.z;
  const u16* A = z == 0 ? xq : z == 1 ? xk : xv;
  const u16* W = z == 0 ? wq : z == 1 ? wk : wv_;
  const float* bias = z == 0 ? bq : z == 1 ? bk : bv;
  const int s0 = blockIdx.x * 128, n0 = blockIdx.y * 128;
  const int t = threadIdx.x, wvi = t >> 6, lane = t & 63;
  const int m16 = lane & 15, q4 = lane >> 4;
  const int wr = (wvi & 1) * 64, wc = (wvi >> 1) * 64;
  f32x4 acc[4][4];
#pragma unroll
  for (int i = 0; i < 4; ++i)
#pragma unroll
    for (int j = 0; j < 4; ++j) acc[i][j] = (f32x4){0.f, 0.f, 0.f, 0.f};

  gemm_core(A, W, Asm, Bsm, s0, n0, wvi, lane, m16, q4, acc);

  if (z < 2) {
    u16* out = z == 0 ? qb : kb;
    const float scale = z == 0 ? C_SCALE : 1.0f;
#pragma unroll
    for (int j = 0; j < 4; ++j) {
      int n = n0 + wc + j * 16 + m16;
      int h = n >> 6, e = n & 63;
      float bval = bias[n];
#pragma unroll
      for (int i = 0; i < 4; ++i)
#pragma unroll
        for (int r = 0; r < 4; ++r) {
          int s = s0 + wr + i * 16 + q4 * 4 + r;
          int bi = s >> 11, sl = s & 2047;
          out[((size_t)(bi * 16 + h) * 2048 + sl) * 64 + e] =
              f2b((acc[i][j][r] + bval) * scale);
        }
    }
  } else {
    // V: transpose through LDS (stride 136), write vt[b][h][e][2048]
    __syncthreads();
#pragma unroll
    for (int j = 0; j < 4; ++j) {
      int nl = wc + j * 16 + m16;
      float bval = bias[n0 + nl];
#pragma unroll
      for (int i = 0; i < 4; ++i)
#pragma unroll
        for (int r = 0; r < 4; ++r)
          S[nl * 136 + wr + i * 16 + q4 * 4 + r] = f2b(acc[i][j][r] + bval);
    }
    __syncthreads();
    const int bi = s0 >> 11, sl0 = s0 & 2047;
#pragma unroll
    for (int rep = 0; rep < 8; ++rep) {  // 128x128 tile = 2048 int4 units
      int u = rep * 256 + t;
      int rr = u >> 4, cc = (u & 15) * 8;
      int n = n0 + rr, h = n >> 6, e = n & 63;
      *(int4*)(vtb + ((size_t)(bi * 16 + h) * 64 + e) * 2048 + sl0 + cc) =
          *(const int4*)(S + rr * 136 + cc);
    }
  }
}

// ---------------------------------------------------------------------------
// Output GEMM: fp32 out [s][1024]. Grid (64, 8).
// ---------------------------------------------------------------------------
__global__ __launch_bounds__(256, 2) void out_gemm(
    const u16* __restrict__ Z, const u16* __restrict__ Wot,
    const float* __restrict__ bo, float* __restrict__ out) {
  __shared__ u16 S[17408];
  u16* Asm = S;
  u16* Bsm = S + 8192;
  const int s0 = blockIdx.x * 128, n0 = blockIdx.y * 128;
  const int t = threadIdx.x, wvi = t >> 6, lane = t & 63;
  const int m16 = lane & 15, q4 = lane >> 4;
  const int wr = (wvi & 1) * 64, wc = (wvi >> 1) * 64;
  f32x4 acc[4][4];
#pragma unroll
  for (int i = 0; i < 4; ++i)
#pragma unroll
    for (int j = 0; j < 4; ++j) acc[i][j] = (f32x4){0.f, 0.f, 0.f, 0.f};

  gemm_core(Z, Wot, Asm, Bsm, s0, n0, wvi, lane, m16, q4, acc);

#pragma unroll
  for (int j = 0; j < 4; ++j) {
    int n = n0 + wc + j * 16 + m16;
    float bval = bo[n];
#pragma unroll
    for (int i = 0; i < 4; ++i)
#pragma unroll
      for (int r = 0; r < 4; ++r) {
        int s = s0 + wr + i * 16 + q4 * 4 + r;
        out[(size_t)s * 1024 + n] = acc[i][j][r] + bval;
      }
  }
}

// ---------------------------------------------------------------------------
// Flash attention, no-max softmax. Masking via bf16 {1,0} multiply:
// p = exp2(s*m) (masked -> exp2(0)=1, matching score->0-before-softmax).
// Key-permuted K staging so PV runs K=32 MFMA; lsum via ones-MFMA.
// Lane's sa[r]/sb[r] map to ORIGINAL keys kt*64 + bb*32 + q4*8 + r / +4+r,
// so each (qg,bb) needs one aligned int4 of bf16 mask.
// Block: 4 waves x 32 q = 128 q of one (b,h). Grid: 1024, 256 threads.
// ---------------------------------------------------------------------------
__global__ __launch_bounds__(256, 4) void attn(
    const u16* __restrict__ qb, const u16* __restrict__ kb,
    const u16* __restrict__ vt, const u16* __restrict__ mk,
    u16* __restrict__ zb) {
  __shared__ u16 Kl[2][64 * LD];  // permuted-key rows
  __shared__ u16 Vl[2][64 * LD];  // [e][key] natural
  const int id = blockIdx.x;
  const int qi = id >> 6;
  const int bh = id & 63;
  const int b = bh >> 4, h = bh & 15;
  const int t = threadIdx.x, w = t >> 6, lane = t & 63;
  const int m16 = lane & 15, q4 = lane >> 4;
  const size_t bho = (size_t)bh * 2048;
  const u16* qp = qb + bho * 64;
  const u16* kp = kb + bho * 64;
  const u16* vp = vt + bho * 64;  // [e][2048]
  const int qbase = qi * 128 + w * 32;

  bf16x8 qa[2][2];
#pragma unroll
  for (int qg = 0; qg < 2; ++qg)
#pragma unroll
    for (int ks = 0; ks < 2; ++ks)
      qa[qg][ks] = *(const bf16x8*)(qp + (size_t)(qbase + qg * 16 + m16) * 64 + ks * 32 + q4 * 8);

  f32x4 oacc[2][4], lacc[2];
#pragma unroll
  for (int qg = 0; qg < 2; ++qg) {
    lacc[qg] = (f32x4){0.f, 0.f, 0.f, 0.f};
#pragma unroll
    for (int g = 0; g < 4; ++g) oacc[qg][g] = (f32x4){0.f, 0.f, 0.f, 0.f};
  }
  bf16x8 ones;
#pragma unroll
  for (int j = 0; j < 8; ++j) ones[j] = (short)0x3f80;

  // bf16 mask rows for this lane's two q rows; keys contiguous
  const u16* mrow[2];
  mrow[0] = mk + ((size_t)b * 2048 + qbase + m16) * 2048;
  mrow[1] = mk + ((size_t)b * 2048 + qbase + 16 + m16) * 2048;

  const int ch = t & 7, rw = t >> 3;  // rw in 0..31
  const int sK = (((rw >> 2) & 1) * 16) + (((rw >> 3) & 3) * 4) + (rw & 3);

  // prefetch tile 0 + mask 0
  int4 pk0 = *(const int4*)(kp + (size_t)rw * 64 + ch * 8);
  int4 pk1 = *(const int4*)(kp + (size_t)(rw + 32) * 64 + ch * 8);
  int4 pv0 = *(const int4*)(vp + (size_t)rw * 2048 + ch * 8);
  int4 pv1 = *(const int4*)(vp + (size_t)(rw + 32) * 2048 + ch * 8);
  int4 cm[2][2], nm[2][2];
#pragma unroll
  for (int qg = 0; qg < 2; ++qg)
#pragma unroll
    for (int bb = 0; bb < 2; ++bb)
      cm[qg][bb] = *(const int4*)(mrow[qg] + bb * 32 + q4 * 8);
  *(int4*)(&Kl[0][sK * LD + ch * 8]) = pk0;
  *(int4*)(&Kl[0][(sK + 32) * LD + ch * 8]) = pk1;
  *(int4*)(&Vl[0][rw * LD + ch * 8]) = pv0;
  *(int4*)(&Vl[0][(rw + 32) * LD + ch * 8]) = pv1;
  __syncthreads();

  for (int kt = 0; kt < 32; ++kt) {
    const int cur = kt & 1;
    if (kt < 31) {
      const int k0n = (kt + 1) * 64;
      pk0 = *(const int4*)(kp + (size_t)(k0n + rw) * 64 + ch * 8);
      pk1 = *(const int4*)(kp + (size_t)(k0n + rw + 32) * 64 + ch * 8);
      pv0 = *(const int4*)(vp + (size_t)rw * 2048 + k0n + ch * 8);
      pv1 = *(const int4*)(vp + (size_t)(rw + 32) * 2048 + k0n + ch * 8);
#pragma unroll
      for (int qg = 0; qg < 2; ++qg)
#pragma unroll
        for (int bb = 0; bb < 2; ++bb)
          nm[qg][bb] = *(const int4*)(mrow[qg] + k0n + bb * 32 + q4 * 8);
    }

#pragma unroll
    for (int bb = 0; bb < 2; ++bb) {
      bf16x8 kf00 = *(const bf16x8*)(&Kl[cur][(bb * 32 + m16) * LD + q4 * 8]);
      bf16x8 kf01 = *(const bf16x8*)(&Kl[cur][(bb * 32 + m16) * LD + 32 + q4 * 8]);
      bf16x8 kf10 = *(const bf16x8*)(&Kl[cur][(bb * 32 + 16 + m16) * LD + q4 * 8]);
      bf16x8 kf11 = *(const bf16x8*)(&Kl[cur][(bb * 32 + 16 + m16) * LD + 32 + q4 * 8]);
      bf16x8 pa[2];
#pragma unroll
      for (int qg = 0; qg < 2; ++qg) {
        f32x4 sa = (f32x4){0.f, 0.f, 0.f, 0.f};
        f32x4 sb = (f32x4){0.f, 0.f, 0.f, 0.f};
        sa = __builtin_amdgcn_mfma_f32_16x16x32_bf16(kf00, qa[qg][0], sa, 0, 0, 0);
        sa = __builtin_amdgcn_mfma_f32_16x16x32_bf16(kf01, qa[qg][1], sa, 0, 0, 0);
        sb = __builtin_amdgcn_mfma_f32_16x16x32_bf16(kf10, qa[qg][0], sb, 0, 0, 0);
        sb = __builtin_amdgcn_mfma_f32_16x16x32_bf16(kf11, qa[qg][1], sb, 0, 0, 0);
        const int4 mw = cm[qg][bb];
        float p[8];
        p[0] = __builtin_amdgcn_exp2f(sa[0] * blo(mw.x));
        p[1] = __builtin_amdgcn_exp2f(sa[1] * bhi(mw.x));
        p[2] = __builtin_amdgcn_exp2f(sa[2] * blo(mw.y));
        p[3] = __builtin_amdgcn_exp2f(sa[3] * bhi(mw.y));
        p[4] = __builtin_amdgcn_exp2f(sb[0] * blo(mw.z));
        p[5] = __builtin_amdgcn_exp2f(sb[1] * bhi(mw.z));
        p[6] = __builtin_amdgcn_exp2f(sb[2] * blo(mw.w));
        p[7] = __builtin_amdgcn_exp2f(sb[3] * bhi(mw.w));
        union { unsigned u[4]; bf16x8 v; } pu;
        pu.u[0] = pk2(p[0], p[1]);
        pu.u[1] = pk2(p[2], p[3]);
        pu.u[2] = pk2(p[4], p[5]);
        pu.u[3] = pk2(p[6], p[7]);
        pa[qg] = pu.v;
        lacc[qg] = __builtin_amdgcn_mfma_f32_16x16x32_bf16(pa[qg], ones, lacc[qg], 0, 0, 0);
      }
#pragma unroll
      for (int e = 0; e < 4; ++e) {
        bf16x8 vf = *(const bf16x8*)(&Vl[cur][(e * 16 + m16) * LD + bb * 32 + q4 * 8]);
        oacc[0][e] = __builtin_amdgcn_mfma_f32_16x16x32_bf16(pa[0], vf, oacc[0][e], 0, 0, 0);
        oacc[1][e] = __builtin_amdgcn_mfma_f32_16x16x32_bf16(pa[1], vf, oacc[1][e], 0, 0, 0);
      }
    }

    if (kt < 31) {
      const int nxt = cur ^ 1;
      *(int4*)(&Kl[nxt][sK * LD + ch * 8]) = pk0;
      *(int4*)(&Kl[nxt][(sK + 32) * LD + ch * 8]) = pk1;
      *(int4*)(&Vl[nxt][rw * LD + ch * 8]) = pv0;
      *(int4*)(&Vl[nxt][(rw + 32) * LD + ch * 8]) = pv1;
#pragma unroll
      for (int qg = 0; qg < 2; ++qg)
#pragma unroll
        for (int bb = 0; bb < 2; ++bb) cm[qg][bb] = nm[qg][bb];
      __syncthreads();
    }
  }

  // epilogue: lane's lacc reg r IS the denom for q-row q4*4+r (cols replicated)
#pragma unroll
  for (int qg = 0; qg < 2; ++qg) {
#pragma unroll
    for (int r = 0; r < 4; ++r) {
      float inv = 1.f / lacc[qg][r];
      size_t zr = ((size_t)b * 2048 + qbase + qg * 16 + q4 * 4 + r) * 1024 + h * 64;
#pragma unroll
      for (int e = 0; e < 4; ++e) {
        zb[zr + e * 16 + m16] = f2b(oacc[qg][e][r] * inv);
      }
    }
  }
}

// ---------------------------------------------------------------------------
extern "C" void kernel_launch(void* const* d_in, const int* in_sizes, int n_in,
                              void* d_out, int out_size, void* d_ws, size_t ws_size,
                              hipStream_t stream) {
  const float* x_v = (const float*)d_in[0];
  const float* x_k = (const float*)d_in[1];
  const float* x_q = (const float*)d_in[2];
  const int* mask = (const int*)d_in[3];
  const float* Wq = (const float*)d_in[4];
  const float* bq = (const float*)d_in[5];
  const float* Wk = (const float*)d_in[6];
  const float* bk = (const float*)d_in[7];
  const float* Wv = (const float*)d_in[8];
  const float* bv = (const float*)d_in[9];
  const float* Wo = (const float*)d_in[10];
  const float* bo = (const float*)d_in[11];
  float* out = (float*)d_out;

  char* ws = (char*)d_ws;
  size_t off = 0;
  auto alloc_u16 = [&](size_t n) {
    u16* p = (u16*)(ws + off);
    off += n * sizeof(u16);
    return p;
  };
  u16* wq_t = alloc_u16((size_t)16 * 64 * 1024);  // [h][e][d]
  u16* wk_t = alloc_u16((size_t)16 * 64 * 1024);
  u16* wv_t = alloc_u16((size_t)16 * 64 * 1024);
  u16* wo_t = alloc_u16((size_t)1024 * 1024);     // [n][k]
  u16* qb = alloc_u16((size_t)8192 * 1024);       // [b][h][s][e] (pre-scaled)
  u16* kb = alloc_u16((size_t)8192 * 1024);
  u16* vtb = alloc_u16((size_t)8192 * 1024);      // [b][h][e][s]
  u16* xq16 = alloc_u16((size_t)8192 * 1024);     // reused as zb after q-proj
  u16* xk16 = alloc_u16((size_t)8192 * 1024);     // reused as mask16 (32 MB
  u16* xv16 = alloc_u16((size_t)8192 * 1024);     //   spanning xk16+xv16)
  u16* zb = xq16;
  u16* mask16 = xk16;  // written after qkv_gemm consumed xk16/xv16

  transpose_cvt_all<<<dim3(1024), 256, 0, stream>>>(
      Wq, Wk, Wv, Wo, wq_t, wk_t, wv_t, wo_t);
  const int n4 = 8192 * 1024 / 4;
  cvt_bf16_3<<<dim3(512, 3), 256, 0, stream>>>(
      (const float4*)x_q, (const float4*)x_k, (const float4*)x_v,
      (ushort4*)xq16, (ushort4*)xk16, (ushort4*)xv16, n4);
  qkv_gemm<<<dim3(64, 8, 3), 256, 0, stream>>>(
      xq16, xk16, xv16, wq_t, wk_t, wv_t, bq, bk, bv, qb, kb, vtb);
  expand_mask<<<dim3(2048), 256, 0, stream>>>(
      (const int4*)mask, (ushort4*)mask16, 4 * 2048 * 2048 / 4);
  attn<<<dim3(1024), 256, 0, stream>>>(qb, kb, vtb, mask16, zb);
  out_gemm<<<dim3(64, 8), 256, 0, stream>>>(zb, wo_t, bo, out);
}